// Round 6
// baseline (4885.583 us; speedup 1.0000x reference)
//
#include <hip/hip_runtime.h>
#include <hip/hip_bf16.h>
#include <math.h>

constexpr int NN  = 16384;
constexpr int DD  = 64;
constexpr int CC  = 128;
constexpr int OO  = 128;
constexpr int KP1 = 17;
constexpr int SIMN = NN;

// ---------------------------------------------------------------------------
// Init: deg = 0, nbr = self (graceful degradation if topk were to fail)
// ---------------------------------------------------------------------------
__global__ __launch_bounds__(256)
void k_init(int* __restrict__ deg, int* __restrict__ nbr)
{
    int t = blockIdx.x * 256 + threadIdx.x;
    if (t < NN) deg[t] = 0;
    if (t < NN * KP1) nbr[t] = t / KP1;
}

// ---------------------------------------------------------------------------
// Preprocess, one node per block, 128 threads (thread = channel).
// fp64 math from fp32 inputs; writes zn64 (optional), z32, zn32.
// ---------------------------------------------------------------------------
__global__ __launch_bounds__(128)
void k_pre(const float* __restrict__ x_raw, const float* __restrict__ eps,
           const float* __restrict__ col_logit, const float* __restrict__ type_logit,
           const float* __restrict__ W_enc, const float* __restrict__ b_enc,
           const float* __restrict__ W_mu, const float* __restrict__ b_mu,
           const float* __restrict__ W_lv, const float* __restrict__ b_lv,
           double* __restrict__ zn64, float* __restrict__ z32, float* __restrict__ zn32,
           int use64)
{
    const int n = blockIdx.x;
    const int c = threadIdx.x;
    __shared__ double xg[DD];
    __shared__ double hsm[CC];
    __shared__ double zsh[CC];

    if (c < DD) {
        double l = (double)col_logit[c];
        double s = 1.0 / (1.0 + exp(-l * 0.5));          // sigmoid(l / TAU), TAU=2
        double g = fmin(fmax(s * 1.2 - 0.1, 0.0), 1.0);  // * (ZETA-GAMMA) + GAMMA
        xg[c] = (double)x_raw[(size_t)n * DD + c] * g;
    }
    __syncthreads();

    double tg;
    {
        double l = (double)type_logit[0];
        double s = 1.0 / (1.0 + exp(-l * 0.5));
        tg = fmin(fmax(s * 1.2 - 0.1, 0.0), 1.0);
    }

    double h = (double)b_enc[c];
    for (int d = 0; d < DD; d++) h += xg[d] * (double)W_enc[d * CC + c];
    h *= tg;
    hsm[c] = h;
    __syncthreads();

    double mu = (double)b_mu[c], lv = (double)b_lv[c];
    for (int j = 0; j < CC; j++) {
        double hj = hsm[j];
        mu += hj * (double)W_mu[j * CC + c];
        lv += hj * (double)W_lv[j * CC + c];
    }
    lv = fmin(fmax(lv, -10.0), 10.0);
    double z = mu + (double)eps[(size_t)n * CC + c] * exp(0.5 * lv);

    zsh[c] = z * z;
    __syncthreads();
    for (int off2 = 64; off2 > 0; off2 >>= 1) {
        if (c < off2) zsh[c] += zsh[c + off2];
        __syncthreads();
    }
    double rs = 1.0 / sqrt(zsh[0] + 1e-12);
    double zn = z * rs;

    size_t o = (size_t)n * CC + c;
    if (use64) zn64[o] = zn;
    z32[o]  = (float)z;
    zn32[o] = (float)zn;
}

// ---------------------------------------------------------------------------
// Sim stripe GEMM (fp32 VALU): C tile 128x128, 256 threads, 8x8 per thread.
// ---------------------------------------------------------------------------
__global__ __launch_bounds__(256)
void k_sim(const float* __restrict__ zn, int row0, float* __restrict__ sim)
{
    __shared__ __align__(16) float As[32][132];
    __shared__ __align__(16) float Bs[32][132];
    const int tid = threadIdx.x;
    const int gm = tid >> 4;
    const int gn = tid & 15;
    float acc[8][8];
    #pragma unroll
    for (int i = 0; i < 8; i++)
        #pragma unroll
        for (int j = 0; j < 8; j++) acc[i][j] = 0.f;

    const int am0 = row0 + blockIdx.x * 128;
    const int bn0 = blockIdx.y * 128;
    const int lm  = tid & 127;
    const int lk  = (tid >> 7) * 16;

    for (int k0 = 0; k0 < CC; k0 += 32) {
        const float4* ap = (const float4*)(zn + (size_t)(am0 + lm) * CC + k0 + lk);
        const float4* bp = (const float4*)(zn + (size_t)(bn0 + lm) * CC + k0 + lk);
        float av[16], bv[16];
        *(float4*)&av[0]  = ap[0]; *(float4*)&av[4]  = ap[1];
        *(float4*)&av[8]  = ap[2]; *(float4*)&av[12] = ap[3];
        *(float4*)&bv[0]  = bp[0]; *(float4*)&bv[4]  = bp[1];
        *(float4*)&bv[8]  = bp[2]; *(float4*)&bv[12] = bp[3];
        __syncthreads();
        #pragma unroll
        for (int i = 0; i < 16; i++) { As[lk + i][lm] = av[i]; Bs[lk + i][lm] = bv[i]; }
        __syncthreads();
        #pragma unroll 8
        for (int k = 0; k < 32; k++) {
            float aF[8], bF[8];
            *(float4*)&aF[0] = *(const float4*)&As[k][gm * 8];
            *(float4*)&aF[4] = *(const float4*)&As[k][gm * 8 + 4];
            *(float4*)&bF[0] = *(const float4*)&Bs[k][gn * 8];
            *(float4*)&bF[4] = *(const float4*)&Bs[k][gn * 8 + 4];
            #pragma unroll
            for (int i = 0; i < 8; i++)
                #pragma unroll
                for (int j = 0; j < 8; j++) acc[i][j] += aF[i] * bF[j];
        }
    }
    #pragma unroll
    for (int i = 0; i < 8; i++) {
        size_t r = (size_t)(blockIdx.x * 128 + gm * 8 + i) * SIMN + bn0 + gn * 8;
        *(float4*)&sim[r]     = make_float4(acc[i][0], acc[i][1], acc[i][2], acc[i][3]);
        *(float4*)&sim[r + 4] = make_float4(acc[i][4], acc[i][5], acc[i][6], acc[i][7]);
    }
}

// ---------------------------------------------------------------------------
// Per-row top-32 (fp32 scan) -> re-rank (fp64 if use64, else fp32-in-fp64) ->
// exact top-17. One 64-lane wave per row.
// ---------------------------------------------------------------------------
__global__ __launch_bounds__(64)
void k_topk(const float* __restrict__ sim, int row0,
            const double* __restrict__ zn64, const float* __restrict__ zn32,
            int* __restrict__ nbr, int use64)
{
    const int lr = blockIdx.x;
    const int r  = row0 + lr;
    const int lane = threadIdx.x;

    float lval[16]; int lidx[16];
    #pragma unroll
    for (int i = 0; i < 16; i++) { lval[i] = -3.0e38f; lidx[i] = 0; }
    float vmin = -3.0e38f; int pmin = 0;

    const float* srow = sim + (size_t)lr * SIMN;
    for (int t = 0; t < SIMN / 64; t++) {
        int j = lane + t * 64;
        float v = srow[j];
        if (v > vmin) {
            #pragma unroll
            for (int i = 0; i < 16; i++) if (i == pmin) { lval[i] = v; lidx[i] = j; }
            vmin = lval[0]; pmin = 0;
            #pragma unroll
            for (int i = 1; i < 16; i++) if (lval[i] < vmin) { vmin = lval[i]; pmin = i; }
        }
    }

    __shared__ float cv[1024]; __shared__ int ci[1024];
    #pragma unroll
    for (int i = 0; i < 16; i++) { cv[lane * 16 + i] = lval[i]; ci[lane * 16 + i] = lidx[i]; }
    __syncthreads();

    __shared__ int gi[32];
    if (lane == 0) {
        float gv[32];
        int   gidx[32];
        for (int i = 0; i < 32; i++) { gv[i] = -3.0e38f; gidx[i] = 0; }
        float gmin = -3.0e38f; int gpm = 0;
        for (int t = 0; t < 1024; t++) {
            float v = cv[t];
            if (v > gmin) {
                gv[gpm] = v; gidx[gpm] = ci[t];
                gmin = gv[0]; gpm = 0;
                for (int i = 1; i < 32; i++) if (gv[i] < gmin) { gmin = gv[i]; gpm = i; }
            }
        }
        for (int i = 0; i < 32; i++) gi[i] = gidx[i];
    }
    __syncthreads();

    // re-rank the 32 candidates against row r (fp64 accumulation)
    __shared__ double q[CC];
    if (use64) { for (int t = lane; t < CC; t += 64) q[t] = zn64[(size_t)r * CC + t]; }
    else       { for (int t = lane; t < CC; t += 64) q[t] = (double)zn32[(size_t)r * CC + t]; }
    __syncthreads();
    __shared__ double dv[32];
    if (lane < 32) {
        int cidx = gi[lane];
        if ((unsigned)cidx >= (unsigned)NN) cidx = 0;
        double s = 0.0;
        if (use64) {
            const double* zr = zn64 + (size_t)cidx * CC;
            for (int k = 0; k < CC; k++) s += q[k] * zr[k];
        } else {
            const float* zr = zn32 + (size_t)cidx * CC;
            for (int k = 0; k < CC; k++) s += q[k] * (double)zr[k];
        }
        dv[lane] = s;
    }
    __syncthreads();
    if (lane == 0) {
        unsigned used = 0u;
        for (int t = 0; t < KP1; t++) {
            double bv = 0.0; int bidx = 0; int bpos = 0; bool found = false;
            for (int i = 0; i < 32; i++) {
                if (used & (1u << i)) continue;
                double v = dv[i]; int ix = gi[i];
                if (!found || v > bv || (v == bv && ix < bidx)) { bv = v; bidx = ix; bpos = i; found = true; }
            }
            used |= (1u << bpos);
            nbr[(size_t)r * KP1 + t] = bidx;
        }
    }
}

// ---------------------------------------------------------------------------
// CSR build: count -> scan(256 threads) -> fill. All index-guarded.
// ---------------------------------------------------------------------------
__global__ __launch_bounds__(256)
void k_count(const int* __restrict__ nbr, int* __restrict__ deg)
{
    int e = blockIdx.x * 256 + threadIdx.x;
    if (e >= NN * KP1) return;
    int i = e / KP1;
    int dst = nbr[e];
    if (dst != i && (unsigned)dst < (unsigned)NN) atomicAdd(&deg[dst], 1);
}

__global__ __launch_bounds__(256)
void k_scan(const int* __restrict__ deg, int* __restrict__ rp, int* __restrict__ wp)
{
    __shared__ int s[256];
    __shared__ int carry;
    const int tid = threadIdx.x;
    if (tid == 0) carry = 0;
    __syncthreads();
    for (int ch = 0; ch < NN / 256; ch++) {
        int v = deg[ch * 256 + tid];
        s[tid] = v;
        __syncthreads();
        for (int off2 = 1; off2 < 256; off2 <<= 1) {
            int t = (tid >= off2) ? s[tid - off2] : 0;
            __syncthreads();
            s[tid] += t;
            __syncthreads();
        }
        int inc = s[tid];
        int base = carry;
        rp[ch * 256 + tid + 1] = base + inc;
        wp[ch * 256 + tid]     = base + inc - v;
        __syncthreads();
        if (tid == 255) carry = base + inc;
        __syncthreads();
    }
    if (tid == 0) rp[0] = 0;
}

__global__ __launch_bounds__(256)
void k_fill(const int* __restrict__ nbr, int* __restrict__ wp, int* __restrict__ es)
{
    int e = blockIdx.x * 256 + threadIdx.x;
    if (e >= NN * KP1) return;
    int i = e / KP1;
    int dst = nbr[e];
    if (dst != i && (unsigned)dst < (unsigned)NN) {
        int pos = atomicAdd(&wp[dst], 1);
        if ((unsigned)pos < (unsigned)(NN * KP1)) es[pos] = i;
    }
}

// ---------------------------------------------------------------------------
// Mean of in-neighbors
// ---------------------------------------------------------------------------
__global__ __launch_bounds__(128)
void k_gather(const float* __restrict__ x, const int* __restrict__ rp,
              const int* __restrict__ es, float* __restrict__ meanb)
{
    int n = blockIdx.x, c = threadIdx.x;
    int b = rp[n], e2 = rp[n + 1];
    if (b < 0) b = 0;
    if (e2 > NN * KP1) e2 = NN * KP1;
    float acc = 0.f;
    int cnt = 0;
    for (int t = b; t < e2; t++) {
        int s = es[t];
        if ((unsigned)s < (unsigned)NN) { acc += x[(size_t)s * CC + c]; cnt++; }
    }
    meanb[(size_t)n * CC + c] = acc / fmaxf((float)cnt, 1.0f);
}

// ---------------------------------------------------------------------------
// SAGE layer: out = relu(a@Ws + mean@Wn + b), 8 nodes/block
// ---------------------------------------------------------------------------
__global__ __launch_bounds__(128)
void k_layer(const float* __restrict__ a, const float* __restrict__ mb,
             const float* __restrict__ Ws, const float* __restrict__ Wn,
             const float* __restrict__ bias, float* __restrict__ out)
{
    __shared__ float as[8][CC], ms[8][CC];
    const int tid = threadIdx.x;
    const int n0 = blockIdx.x * 8;
    #pragma unroll
    for (int m = 0; m < 8; m++) {
        as[m][tid] = a[(size_t)(n0 + m) * CC + tid];
        ms[m][tid] = mb[(size_t)(n0 + m) * CC + tid];
    }
    __syncthreads();
    float acc[8];
    #pragma unroll
    for (int m = 0; m < 8; m++) acc[m] = bias[tid];
    for (int j = 0; j < CC; j++) {
        float ws = Ws[j * CC + tid], wn = Wn[j * CC + tid];
        #pragma unroll
        for (int m = 0; m < 8; m++) acc[m] += as[m][j] * ws + ms[m][j] * wn;
    }
    #pragma unroll
    for (int m = 0; m < 8; m++)
        out[(size_t)(n0 + m) * CC + tid] = fmaxf(acc[m], 0.f);
}

// ---------------------------------------------------------------------------
// Head: out = h2 @ W_head + b_head, stored FP32 (reference returns float32)
// ---------------------------------------------------------------------------
__global__ __launch_bounds__(128)
void k_head(const float* __restrict__ h2, const float* __restrict__ W,
            const float* __restrict__ bias, float* __restrict__ out)
{
    __shared__ float hsh[8][CC];
    const int tid = threadIdx.x;
    const int n0 = blockIdx.x * 8;
    #pragma unroll
    for (int m = 0; m < 8; m++) hsh[m][tid] = h2[(size_t)(n0 + m) * CC + tid];
    __syncthreads();
    float acc[8];
    #pragma unroll
    for (int m = 0; m < 8; m++) acc[m] = bias[tid];
    for (int j = 0; j < CC; j++) {
        float w = W[j * OO + tid];
        #pragma unroll
        for (int m = 0; m < 8; m++) acc[m] += hsh[m][j] * w;
    }
    #pragma unroll
    for (int m = 0; m < 8; m++)
        out[(size_t)(n0 + m) * OO + tid] = acc[m];
}

// ---------------------------------------------------------------------------
extern "C" void kernel_launch(void* const* d_in, const int* in_sizes, int n_in,
                              void* d_out, int out_size, void* d_ws, size_t ws_size,
                              hipStream_t stream)
{
    const float* x_raw      = (const float*)d_in[0];
    const float* eps        = (const float*)d_in[1];
    const float* col_logit  = (const float*)d_in[2];
    const float* type_logit = (const float*)d_in[3];
    const float* W_enc      = (const float*)d_in[4];
    const float* b_enc      = (const float*)d_in[5];
    const float* W_mu       = (const float*)d_in[6];
    const float* b_mu       = (const float*)d_in[7];
    const float* W_lv       = (const float*)d_in[8];
    const float* b_lv       = (const float*)d_in[9];
    const float* W_self1    = (const float*)d_in[10];
    const float* W_nbr1     = (const float*)d_in[11];
    const float* b1         = (const float*)d_in[12];
    const float* W_self2    = (const float*)d_in[13];
    const float* W_nbr2     = (const float*)d_in[14];
    const float* b2         = (const float*)d_in[15];
    const float* W_head     = (const float*)d_in[16];
    const float* b_head     = (const float*)d_in[17];
    float* out              = (float*)d_out;   // fp32 output, per reference dtype

    char* base = (char*)d_ws;
    size_t off = 0;
    auto alloc = [&](size_t bytes) { size_t o = off; off = (off + bytes + 255) & ~(size_t)255; return o; };

    const size_t MAT  = (size_t)NN * CC * 4;   // 8.39 MB

    float* z32   = (float*)(base + alloc(MAT));
    float* zn32  = (float*)(base + alloc(MAT));
    float* slotD = (float*)(base + alloc(MAT));   // sim (S=128 overlay) then h1
    float* meanb = (float*)(base + alloc(MAT));
    int*   nbr   = (int*)(base + alloc((size_t)NN * KP1 * 4));
    int*   deg   = (int*)(base + alloc((size_t)NN * 4));
    int*   rp    = (int*)(base + alloc((size_t)(NN + 1) * 4));
    int*   wp    = (int*)(base + alloc((size_t)NN * 4));
    int*   es    = (int*)(base + alloc((size_t)NN * KP1 * 4));
    size_t fixed_small = off;                     // ~36.3 MB

    // optional fp64 zn (16.78 MB)
    int use64 = (ws_size >= fixed_small + (size_t)NN * CC * 8 + 4096) ? 1 : 0;
    double* zn64 = nullptr;
    if (use64) zn64 = (double*)(base + alloc((size_t)NN * CC * 8));

    // optional dedicated sim stripe beyond the fixed pool
    size_t avail = (ws_size > off) ? (ws_size - off - 4096) : 0;
    int S = 2048;
    while (S > 128 && (size_t)S * SIMN * 4 > avail) S >>= 1;
    float* sim;
    if ((size_t)S * SIMN * 4 <= avail && S > 128) {
        sim = (float*)(base + alloc((size_t)S * SIMN * 4));
    } else {
        S = 128;                                  // overlay: fits exactly in slotD
        sim = slotD;
    }

    float* h1 = slotD;                            // after stripes, slotD becomes h1
    float* h2 = zn32;                             // zn32 dead after topk

    k_init<<<(NN * KP1 + 255) / 256, 256, 0, stream>>>(deg, nbr);

    k_pre<<<NN, 128, 0, stream>>>(x_raw, eps, col_logit, type_logit,
                                  W_enc, b_enc, W_mu, b_mu, W_lv, b_lv,
                                  zn64, z32, zn32, use64);

    for (int row0 = 0; row0 < NN; row0 += S) {
        dim3 g(S / 128, SIMN / 128);
        k_sim<<<g, 256, 0, stream>>>(zn32, row0, sim);
        k_topk<<<S, 64, 0, stream>>>(sim, row0, zn64, zn32, nbr, use64);
    }

    int eb = (NN * KP1 + 255) / 256;
    k_count<<<eb, 256, 0, stream>>>(nbr, deg);
    k_scan<<<1, 256, 0, stream>>>(deg, rp, wp);
    k_fill<<<eb, 256, 0, stream>>>(nbr, wp, es);

    k_gather<<<NN, 128, 0, stream>>>(z32, rp, es, meanb);
    k_layer<<<NN / 8, 128, 0, stream>>>(z32, meanb, W_self1, W_nbr1, b1, h1);
    k_gather<<<NN, 128, 0, stream>>>(h1, rp, es, meanb);
    k_layer<<<NN / 8, 128, 0, stream>>>(h1, meanb, W_self2, W_nbr2, b2, h2);
    k_head<<<NN / 8, 128, 0, stream>>>(h2, W_head, b_head, out);

    (void)in_sizes; (void)n_in; (void)out_size;
}

// Round 7
// 3625.211 us; speedup vs baseline: 1.3477x; 1.3477x over previous
//
#include <hip/hip_runtime.h>
#include <hip/hip_bf16.h>
#include <math.h>

constexpr int NN  = 16384;
constexpr int DD  = 64;
constexpr int CC  = 128;
constexpr int OO  = 128;
constexpr int KP1 = 17;
constexpr int SIMN = NN;

// ---------------------------------------------------------------------------
// Init: deg = 0, nbr = self (graceful degradation if topk were to fail)
// ---------------------------------------------------------------------------
__global__ __launch_bounds__(256)
void k_init(int* __restrict__ deg, int* __restrict__ nbr)
{
    int t = blockIdx.x * 256 + threadIdx.x;
    if (t < NN) deg[t] = 0;
    if (t < NN * KP1) nbr[t] = t / KP1;
}

// ---------------------------------------------------------------------------
// Preprocess, one node per block, 128 threads (thread = channel).
// fp64 math from fp32 inputs; writes zn64 (optional), z32, zn32.
// ---------------------------------------------------------------------------
__global__ __launch_bounds__(128)
void k_pre(const float* __restrict__ x_raw, const float* __restrict__ eps,
           const float* __restrict__ col_logit, const float* __restrict__ type_logit,
           const float* __restrict__ W_enc, const float* __restrict__ b_enc,
           const float* __restrict__ W_mu, const float* __restrict__ b_mu,
           const float* __restrict__ W_lv, const float* __restrict__ b_lv,
           double* __restrict__ zn64, float* __restrict__ z32, float* __restrict__ zn32,
           int use64)
{
    const int n = blockIdx.x;
    const int c = threadIdx.x;
    __shared__ double xg[DD];
    __shared__ double hsm[CC];
    __shared__ double zsh[CC];

    if (c < DD) {
        double l = (double)col_logit[c];
        double s = 1.0 / (1.0 + exp(-l * 0.5));          // sigmoid(l / TAU), TAU=2
        double g = fmin(fmax(s * 1.2 - 0.1, 0.0), 1.0);  // * (ZETA-GAMMA) + GAMMA
        xg[c] = (double)x_raw[(size_t)n * DD + c] * g;
    }
    __syncthreads();

    double tg;
    {
        double l = (double)type_logit[0];
        double s = 1.0 / (1.0 + exp(-l * 0.5));
        tg = fmin(fmax(s * 1.2 - 0.1, 0.0), 1.0);
    }

    double h = (double)b_enc[c];
    for (int d = 0; d < DD; d++) h += xg[d] * (double)W_enc[d * CC + c];
    h *= tg;
    hsm[c] = h;
    __syncthreads();

    double mu = (double)b_mu[c], lv = (double)b_lv[c];
    for (int j = 0; j < CC; j++) {
        double hj = hsm[j];
        mu += hj * (double)W_mu[j * CC + c];
        lv += hj * (double)W_lv[j * CC + c];
    }
    lv = fmin(fmax(lv, -10.0), 10.0);
    double z = mu + (double)eps[(size_t)n * CC + c] * exp(0.5 * lv);

    zsh[c] = z * z;
    __syncthreads();
    for (int off2 = 64; off2 > 0; off2 >>= 1) {
        if (c < off2) zsh[c] += zsh[c + off2];
        __syncthreads();
    }
    double rs = 1.0 / sqrt(zsh[0] + 1e-12);
    double zn = z * rs;

    size_t o = (size_t)n * CC + c;
    if (use64) zn64[o] = zn;
    z32[o]  = (float)z;
    zn32[o] = (float)zn;
}

// ---------------------------------------------------------------------------
// Sim stripe GEMM (fp32 VALU): C tile 128x128, 256 threads, 8x8 per thread.
// ---------------------------------------------------------------------------
__global__ __launch_bounds__(256)
void k_sim(const float* __restrict__ zn, int row0, float* __restrict__ sim)
{
    __shared__ __align__(16) float As[32][132];
    __shared__ __align__(16) float Bs[32][132];
    const int tid = threadIdx.x;
    const int gm = tid >> 4;
    const int gn = tid & 15;
    float acc[8][8];
    #pragma unroll
    for (int i = 0; i < 8; i++)
        #pragma unroll
        for (int j = 0; j < 8; j++) acc[i][j] = 0.f;

    const int am0 = row0 + blockIdx.x * 128;
    const int bn0 = blockIdx.y * 128;
    const int lm  = tid & 127;
    const int lk  = (tid >> 7) * 16;

    for (int k0 = 0; k0 < CC; k0 += 32) {
        const float4* ap = (const float4*)(zn + (size_t)(am0 + lm) * CC + k0 + lk);
        const float4* bp = (const float4*)(zn + (size_t)(bn0 + lm) * CC + k0 + lk);
        float av[16], bv[16];
        *(float4*)&av[0]  = ap[0]; *(float4*)&av[4]  = ap[1];
        *(float4*)&av[8]  = ap[2]; *(float4*)&av[12] = ap[3];
        *(float4*)&bv[0]  = bp[0]; *(float4*)&bv[4]  = bp[1];
        *(float4*)&bv[8]  = bp[2]; *(float4*)&bv[12] = bp[3];
        __syncthreads();
        #pragma unroll
        for (int i = 0; i < 16; i++) { As[lk + i][lm] = av[i]; Bs[lk + i][lm] = bv[i]; }
        __syncthreads();
        #pragma unroll 8
        for (int k = 0; k < 32; k++) {
            float aF[8], bF[8];
            *(float4*)&aF[0] = *(const float4*)&As[k][gm * 8];
            *(float4*)&aF[4] = *(const float4*)&As[k][gm * 8 + 4];
            *(float4*)&bF[0] = *(const float4*)&Bs[k][gn * 8];
            *(float4*)&bF[4] = *(const float4*)&Bs[k][gn * 8 + 4];
            #pragma unroll
            for (int i = 0; i < 8; i++)
                #pragma unroll
                for (int j = 0; j < 8; j++) acc[i][j] += aF[i] * bF[j];
        }
    }
    #pragma unroll
    for (int i = 0; i < 8; i++) {
        size_t r = (size_t)(blockIdx.x * 128 + gm * 8 + i) * SIMN + bn0 + gn * 8;
        *(float4*)&sim[r]     = make_float4(acc[i][0], acc[i][1], acc[i][2], acc[i][3]);
        *(float4*)&sim[r + 4] = make_float4(acc[i][4], acc[i][5], acc[i][6], acc[i][7]);
    }
}

// ---------------------------------------------------------------------------
// Top-k v2: 256 threads (4 waves) per row.
// float4 prefetched scan, per-lane top-8, per-wave shuffle-extraction of
// top-32, 128-entry block merge, fp64 re-rank -> exact top-17.
// ---------------------------------------------------------------------------
__device__ __forceinline__ void ins8(float v, int j, float lval[8], int lidx[8],
                                     float& vmin, int& pmin)
{
    if (v > vmin) {
        #pragma unroll
        for (int i = 0; i < 8; i++) if (i == pmin) { lval[i] = v; lidx[i] = j; }
        vmin = lval[0]; pmin = 0;
        #pragma unroll
        for (int i = 1; i < 8; i++) if (lval[i] < vmin) { vmin = lval[i]; pmin = i; }
    }
}

__global__ __launch_bounds__(256)
void k_topk(const float* __restrict__ sim, int row0,
            const double* __restrict__ zn64, const float* __restrict__ zn32,
            int* __restrict__ nbr, int use64)
{
    const int lr   = blockIdx.x;
    const int r    = row0 + lr;
    const int tid  = threadIdx.x;
    const int lane = tid & 63;
    const int wv   = tid >> 6;

    // ---- phase 1: strided float4 scan, per-lane top-8 ----
    float lval[8]; int lidx[8];
    #pragma unroll
    for (int i = 0; i < 8; i++) { lval[i] = -3.0e38f; lidx[i] = 0; }
    float vmin = -3.0e38f; int pmin = 0;

    const float4* srow4 = (const float4*)(sim + (size_t)lr * SIMN);
    float4 vc = srow4[tid];
    #pragma unroll 4
    for (int t = 0; t < 16; t++) {
        float4 vn = vc;
        if (t < 15) vn = srow4[tid + (t + 1) * 256];
        int base = (tid + t * 256) * 4;
        float m4 = fmaxf(fmaxf(vc.x, vc.y), fmaxf(vc.z, vc.w));
        if (m4 > vmin) {
            ins8(vc.x, base + 0, lval, lidx, vmin, pmin);
            ins8(vc.y, base + 1, lval, lidx, vmin, pmin);
            ins8(vc.z, base + 2, lval, lidx, vmin, pmin);
            ins8(vc.w, base + 3, lval, lidx, vmin, pmin);
        }
        vc = vn;
    }

    // ---- phase 2: per-wave top-32 extraction via butterfly argmax ----
    __shared__ float wcv[128];
    __shared__ int   wci[128];

    float lm = -3.0e38f; int lmslot = 0;
    #pragma unroll
    for (int i = 0; i < 8; i++) if (lval[i] > lm) { lm = lval[i]; lmslot = i; }
    int lmidx = 0;
    #pragma unroll
    for (int i = 0; i < 8; i++) if (i == lmslot) lmidx = lidx[i];

    for (int rd = 0; rd < 32; rd++) {
        float m = lm; int src = lane; int midx = lmidx;
        #pragma unroll
        for (int mask = 1; mask < 64; mask <<= 1) {
            float om  = __shfl_xor(m, mask);
            int   osc = __shfl_xor(src, mask);
            int   omx = __shfl_xor(midx, mask);
            if (om > m || (om == m && omx < midx)) { m = om; src = osc; midx = omx; }
        }
        if (lane == 0) { wcv[wv * 32 + rd] = m; wci[wv * 32 + rd] = midx; }
        if (lane == src) {
            #pragma unroll
            for (int i = 0; i < 8; i++) if (i == lmslot) lval[i] = -3.0e38f;
            lm = -3.0e38f; lmslot = 0;
            #pragma unroll
            for (int i = 0; i < 8; i++) if (lval[i] > lm) { lm = lval[i]; lmslot = i; }
            lmidx = 0;
            #pragma unroll
            for (int i = 0; i < 8; i++) if (i == lmslot) lmidx = lidx[i];
        }
    }
    __syncthreads();

    // ---- phase 3: block merge of 128 candidates -> top-32 (serial, proven) ----
    __shared__ int gi[32];
    if (tid == 0) {
        float gv[32]; int gidx[32];
        for (int i = 0; i < 32; i++) { gv[i] = -3.0e38f; gidx[i] = 0; }
        float gmin = -3.0e38f; int gpm = 0;
        for (int t = 0; t < 128; t++) {
            float v = wcv[t];
            if (v > gmin) {
                gv[gpm] = v; gidx[gpm] = wci[t];
                gmin = gv[0]; gpm = 0;
                for (int i = 1; i < 32; i++) if (gv[i] < gmin) { gmin = gv[i]; gpm = i; }
            }
        }
        for (int i = 0; i < 32; i++) gi[i] = gidx[i];
    }
    __syncthreads();

    // ---- phase 4: fp64 re-rank of 32 candidates -> exact top-17 ----
    __shared__ double q[CC];
    if (tid < CC) {
        q[tid] = use64 ? zn64[(size_t)r * CC + tid] : (double)zn32[(size_t)r * CC + tid];
    }
    __syncthreads();
    __shared__ double dv[32];
    if (tid < 32) {
        int cidx = gi[tid];
        if ((unsigned)cidx >= (unsigned)NN) cidx = 0;
        double s = 0.0;
        if (use64) {
            const double* zr = zn64 + (size_t)cidx * CC;
            for (int k = 0; k < CC; k++) s += q[k] * zr[k];
        } else {
            const float* zr = zn32 + (size_t)cidx * CC;
            for (int k = 0; k < CC; k++) s += q[k] * (double)zr[k];
        }
        dv[tid] = s;
    }
    __syncthreads();
    if (tid == 0) {
        unsigned used = 0u;
        for (int t = 0; t < KP1; t++) {
            double bv = 0.0; int bidx = 0; int bpos = 0; bool found = false;
            for (int i = 0; i < 32; i++) {
                if (used & (1u << i)) continue;
                double v = dv[i]; int ix = gi[i];
                if (!found || v > bv || (v == bv && ix < bidx)) { bv = v; bidx = ix; bpos = i; found = true; }
            }
            used |= (1u << bpos);
            nbr[(size_t)r * KP1 + t] = bidx;
        }
    }
}

// ---------------------------------------------------------------------------
// CSR build: count -> scan(256 threads) -> fill. All index-guarded.
// ---------------------------------------------------------------------------
__global__ __launch_bounds__(256)
void k_count(const int* __restrict__ nbr, int* __restrict__ deg)
{
    int e = blockIdx.x * 256 + threadIdx.x;
    if (e >= NN * KP1) return;
    int i = e / KP1;
    int dst = nbr[e];
    if (dst != i && (unsigned)dst < (unsigned)NN) atomicAdd(&deg[dst], 1);
}

__global__ __launch_bounds__(256)
void k_scan(const int* __restrict__ deg, int* __restrict__ rp, int* __restrict__ wp)
{
    __shared__ int s[256];
    __shared__ int carry;
    const int tid = threadIdx.x;
    if (tid == 0) carry = 0;
    __syncthreads();
    for (int ch = 0; ch < NN / 256; ch++) {
        int v = deg[ch * 256 + tid];
        s[tid] = v;
        __syncthreads();
        for (int off2 = 1; off2 < 256; off2 <<= 1) {
            int t = (tid >= off2) ? s[tid - off2] : 0;
            __syncthreads();
            s[tid] += t;
            __syncthreads();
        }
        int inc = s[tid];
        int base = carry;
        rp[ch * 256 + tid + 1] = base + inc;
        wp[ch * 256 + tid]     = base + inc - v;
        __syncthreads();
        if (tid == 255) carry = base + inc;
        __syncthreads();
    }
    if (tid == 0) rp[0] = 0;
}

__global__ __launch_bounds__(256)
void k_fill(const int* __restrict__ nbr, int* __restrict__ wp, int* __restrict__ es)
{
    int e = blockIdx.x * 256 + threadIdx.x;
    if (e >= NN * KP1) return;
    int i = e / KP1;
    int dst = nbr[e];
    if (dst != i && (unsigned)dst < (unsigned)NN) {
        int pos = atomicAdd(&wp[dst], 1);
        if ((unsigned)pos < (unsigned)(NN * KP1)) es[pos] = i;
    }
}

// ---------------------------------------------------------------------------
// Mean of in-neighbors
// ---------------------------------------------------------------------------
__global__ __launch_bounds__(128)
void k_gather(const float* __restrict__ x, const int* __restrict__ rp,
              const int* __restrict__ es, float* __restrict__ meanb)
{
    int n = blockIdx.x, c = threadIdx.x;
    int b = rp[n], e2 = rp[n + 1];
    if (b < 0) b = 0;
    if (e2 > NN * KP1) e2 = NN * KP1;
    float acc = 0.f;
    int cnt = 0;
    for (int t = b; t < e2; t++) {
        int s = es[t];
        if ((unsigned)s < (unsigned)NN) { acc += x[(size_t)s * CC + c]; cnt++; }
    }
    meanb[(size_t)n * CC + c] = acc / fmaxf((float)cnt, 1.0f);
}

// ---------------------------------------------------------------------------
// SAGE layer: out = relu(a@Ws + mean@Wn + b), 8 nodes/block
// ---------------------------------------------------------------------------
__global__ __launch_bounds__(128)
void k_layer(const float* __restrict__ a, const float* __restrict__ mb,
             const float* __restrict__ Ws, const float* __restrict__ Wn,
             const float* __restrict__ bias, float* __restrict__ out)
{
    __shared__ float as[8][CC], ms[8][CC];
    const int tid = threadIdx.x;
    const int n0 = blockIdx.x * 8;
    #pragma unroll
    for (int m = 0; m < 8; m++) {
        as[m][tid] = a[(size_t)(n0 + m) * CC + tid];
        ms[m][tid] = mb[(size_t)(n0 + m) * CC + tid];
    }
    __syncthreads();
    float acc[8];
    #pragma unroll
    for (int m = 0; m < 8; m++) acc[m] = bias[tid];
    for (int j = 0; j < CC; j++) {
        float ws = Ws[j * CC + tid], wn = Wn[j * CC + tid];
        #pragma unroll
        for (int m = 0; m < 8; m++) acc[m] += as[m][j] * ws + ms[m][j] * wn;
    }
    #pragma unroll
    for (int m = 0; m < 8; m++)
        out[(size_t)(n0 + m) * CC + tid] = fmaxf(acc[m], 0.f);
}

// ---------------------------------------------------------------------------
// Head: out = h2 @ W_head + b_head, stored FP32 (reference returns float32)
// ---------------------------------------------------------------------------
__global__ __launch_bounds__(128)
void k_head(const float* __restrict__ h2, const float* __restrict__ W,
            const float* __restrict__ bias, float* __restrict__ out)
{
    __shared__ float hsh[8][CC];
    const int tid = threadIdx.x;
    const int n0 = blockIdx.x * 8;
    #pragma unroll
    for (int m = 0; m < 8; m++) hsh[m][tid] = h2[(size_t)(n0 + m) * CC + tid];
    __syncthreads();
    float acc[8];
    #pragma unroll
    for (int m = 0; m < 8; m++) acc[m] = bias[tid];
    for (int j = 0; j < CC; j++) {
        float w = W[j * OO + tid];
        #pragma unroll
        for (int m = 0; m < 8; m++) acc[m] += hsh[m][j] * w;
    }
    #pragma unroll
    for (int m = 0; m < 8; m++)
        out[(size_t)(n0 + m) * OO + tid] = acc[m];
}

// ---------------------------------------------------------------------------
extern "C" void kernel_launch(void* const* d_in, const int* in_sizes, int n_in,
                              void* d_out, int out_size, void* d_ws, size_t ws_size,
                              hipStream_t stream)
{
    const float* x_raw      = (const float*)d_in[0];
    const float* eps        = (const float*)d_in[1];
    const float* col_logit  = (const float*)d_in[2];
    const float* type_logit = (const float*)d_in[3];
    const float* W_enc      = (const float*)d_in[4];
    const float* b_enc      = (const float*)d_in[5];
    const float* W_mu       = (const float*)d_in[6];
    const float* b_mu       = (const float*)d_in[7];
    const float* W_lv       = (const float*)d_in[8];
    const float* b_lv       = (const float*)d_in[9];
    const float* W_self1    = (const float*)d_in[10];
    const float* W_nbr1     = (const float*)d_in[11];
    const float* b1         = (const float*)d_in[12];
    const float* W_self2    = (const float*)d_in[13];
    const float* W_nbr2     = (const float*)d_in[14];
    const float* b2         = (const float*)d_in[15];
    const float* W_head     = (const float*)d_in[16];
    const float* b_head     = (const float*)d_in[17];
    float* out              = (float*)d_out;   // fp32 output, per reference dtype

    char* base = (char*)d_ws;
    size_t off = 0;
    auto alloc = [&](size_t bytes) { size_t o = off; off = (off + bytes + 255) & ~(size_t)255; return o; };

    const size_t MAT  = (size_t)NN * CC * 4;   // 8.39 MB

    float* z32   = (float*)(base + alloc(MAT));
    float* zn32  = (float*)(base + alloc(MAT));
    float* slotD = (float*)(base + alloc(MAT));   // sim (S=128 overlay) then h1
    float* meanb = (float*)(base + alloc(MAT));
    int*   nbr   = (int*)(base + alloc((size_t)NN * KP1 * 4));
    int*   deg   = (int*)(base + alloc((size_t)NN * 4));
    int*   rp    = (int*)(base + alloc((size_t)(NN + 1) * 4));
    int*   wp    = (int*)(base + alloc((size_t)NN * 4));
    int*   es    = (int*)(base + alloc((size_t)NN * KP1 * 4));
    size_t fixed_small = off;                     // ~36.3 MB

    // optional fp64 zn (16.78 MB)
    int use64 = (ws_size >= fixed_small + (size_t)NN * CC * 8 + 4096) ? 1 : 0;
    double* zn64 = nullptr;
    if (use64) zn64 = (double*)(base + alloc((size_t)NN * CC * 8));

    // optional dedicated sim stripe beyond the fixed pool
    size_t avail = (ws_size > off) ? (ws_size - off - 4096) : 0;
    int S = 2048;
    while (S > 128 && (size_t)S * SIMN * 4 > avail) S >>= 1;
    float* sim;
    if ((size_t)S * SIMN * 4 <= avail && S > 128) {
        sim = (float*)(base + alloc((size_t)S * SIMN * 4));
    } else {
        S = 128;                                  // overlay: fits exactly in slotD
        sim = slotD;
    }

    float* h1 = slotD;                            // after stripes, slotD becomes h1
    float* h2 = zn32;                             // zn32 dead after topk

    k_init<<<(NN * KP1 + 255) / 256, 256, 0, stream>>>(deg, nbr);

    k_pre<<<NN, 128, 0, stream>>>(x_raw, eps, col_logit, type_logit,
                                  W_enc, b_enc, W_mu, b_mu, W_lv, b_lv,
                                  zn64, z32, zn32, use64);

    for (int row0 = 0; row0 < NN; row0 += S) {
        dim3 g(S / 128, SIMN / 128);
        k_sim<<<g, 256, 0, stream>>>(zn32, row0, sim);
        k_topk<<<S, 256, 0, stream>>>(sim, row0, zn64, zn32, nbr, use64);
    }

    int eb = (NN * KP1 + 255) / 256;
    k_count<<<eb, 256, 0, stream>>>(nbr, deg);
    k_scan<<<1, 256, 0, stream>>>(deg, rp, wp);
    k_fill<<<eb, 256, 0, stream>>>(nbr, wp, es);

    k_gather<<<NN, 128, 0, stream>>>(z32, rp, es, meanb);
    k_layer<<<NN / 8, 128, 0, stream>>>(z32, meanb, W_self1, W_nbr1, b1, h1);
    k_gather<<<NN, 128, 0, stream>>>(h1, rp, es, meanb);
    k_layer<<<NN / 8, 128, 0, stream>>>(h1, meanb, W_self2, W_nbr2, b2, h2);
    k_head<<<NN / 8, 128, 0, stream>>>(h2, W_head, b_head, out);

    (void)in_sizes; (void)n_in; (void)out_size;
}

// Round 8
// 3073.511 us; speedup vs baseline: 1.5896x; 1.1795x over previous
//
#include <hip/hip_runtime.h>
#include <hip/hip_bf16.h>
#include <math.h>

constexpr int NN  = 16384;
constexpr int DD  = 64;
constexpr int CC  = 128;
constexpr int OO  = 128;
constexpr int KP1 = 17;
constexpr int SIMN = NN;
constexpr int TW  = 64;              // pruning tile width
constexpr int NT  = SIMN / TW;       // 256 tiles per row

// ---------------------------------------------------------------------------
// Init: deg = 0, nbr = self (graceful degradation if topk were to fail)
// ---------------------------------------------------------------------------
__global__ __launch_bounds__(256)
void k_init(int* __restrict__ deg, int* __restrict__ nbr)
{
    int t = blockIdx.x * 256 + threadIdx.x;
    if (t < NN) deg[t] = 0;
    if (t < NN * KP1) nbr[t] = t / KP1;
}

// ---------------------------------------------------------------------------
// Preprocess, one node per block, 128 threads (thread = channel).
// fp64 math from fp32 inputs; writes zn64 (optional), z32, zn32.
// ---------------------------------------------------------------------------
__global__ __launch_bounds__(128)
void k_pre(const float* __restrict__ x_raw, const float* __restrict__ eps,
           const float* __restrict__ col_logit, const float* __restrict__ type_logit,
           const float* __restrict__ W_enc, const float* __restrict__ b_enc,
           const float* __restrict__ W_mu, const float* __restrict__ b_mu,
           const float* __restrict__ W_lv, const float* __restrict__ b_lv,
           double* __restrict__ zn64, float* __restrict__ z32, float* __restrict__ zn32,
           int use64)
{
    const int n = blockIdx.x;
    const int c = threadIdx.x;
    __shared__ double xg[DD];
    __shared__ double hsm[CC];
    __shared__ double zsh[CC];

    if (c < DD) {
        double l = (double)col_logit[c];
        double s = 1.0 / (1.0 + exp(-l * 0.5));          // sigmoid(l / TAU), TAU=2
        double g = fmin(fmax(s * 1.2 - 0.1, 0.0), 1.0);  // * (ZETA-GAMMA) + GAMMA
        xg[c] = (double)x_raw[(size_t)n * DD + c] * g;
    }
    __syncthreads();

    double tg;
    {
        double l = (double)type_logit[0];
        double s = 1.0 / (1.0 + exp(-l * 0.5));
        tg = fmin(fmax(s * 1.2 - 0.1, 0.0), 1.0);
    }

    double h = (double)b_enc[c];
    for (int d = 0; d < DD; d++) h += xg[d] * (double)W_enc[d * CC + c];
    h *= tg;
    hsm[c] = h;
    __syncthreads();

    double mu = (double)b_mu[c], lv = (double)b_lv[c];
    for (int j = 0; j < CC; j++) {
        double hj = hsm[j];
        mu += hj * (double)W_mu[j * CC + c];
        lv += hj * (double)W_lv[j * CC + c];
    }
    lv = fmin(fmax(lv, -10.0), 10.0);
    double z = mu + (double)eps[(size_t)n * CC + c] * exp(0.5 * lv);

    zsh[c] = z * z;
    __syncthreads();
    for (int off2 = 64; off2 > 0; off2 >>= 1) {
        if (c < off2) zsh[c] += zsh[c + off2];
        __syncthreads();
    }
    double rs = 1.0 / sqrt(zsh[0] + 1e-12);
    double zn = z * rs;

    size_t o = (size_t)n * CC + c;
    if (use64) zn64[o] = zn;
    z32[o]  = (float)z;
    zn32[o] = (float)zn;
}

// ---------------------------------------------------------------------------
// Sim stripe GEMM (fp32 VALU): C tile 128x128, 256 threads, 8x8 per thread.
// Also emits per-row per-64-col tile maxes (stripe-local rows) for pruning.
// ---------------------------------------------------------------------------
__global__ __launch_bounds__(256)
void k_sim(const float* __restrict__ zn, int row0, float* __restrict__ sim,
           float* __restrict__ simmax)
{
    __shared__ __align__(16) float As[32][132];
    __shared__ __align__(16) float Bs[32][132];
    const int tid = threadIdx.x;
    const int gm = tid >> 4;
    const int gn = tid & 15;
    float acc[8][8];
    #pragma unroll
    for (int i = 0; i < 8; i++)
        #pragma unroll
        for (int j = 0; j < 8; j++) acc[i][j] = 0.f;

    const int am0 = row0 + blockIdx.x * 128;
    const int bn0 = blockIdx.y * 128;
    const int lm  = tid & 127;
    const int lk  = (tid >> 7) * 16;

    for (int k0 = 0; k0 < CC; k0 += 32) {
        const float4* ap = (const float4*)(zn + (size_t)(am0 + lm) * CC + k0 + lk);
        const float4* bp = (const float4*)(zn + (size_t)(bn0 + lm) * CC + k0 + lk);
        float av[16], bv[16];
        *(float4*)&av[0]  = ap[0]; *(float4*)&av[4]  = ap[1];
        *(float4*)&av[8]  = ap[2]; *(float4*)&av[12] = ap[3];
        *(float4*)&bv[0]  = bp[0]; *(float4*)&bv[4]  = bp[1];
        *(float4*)&bv[8]  = bp[2]; *(float4*)&bv[12] = bp[3];
        __syncthreads();
        #pragma unroll
        for (int i = 0; i < 16; i++) { As[lk + i][lm] = av[i]; Bs[lk + i][lm] = bv[i]; }
        __syncthreads();
        #pragma unroll 8
        for (int k = 0; k < 32; k++) {
            float aF[8], bF[8];
            *(float4*)&aF[0] = *(const float4*)&As[k][gm * 8];
            *(float4*)&aF[4] = *(const float4*)&As[k][gm * 8 + 4];
            *(float4*)&bF[0] = *(const float4*)&Bs[k][gn * 8];
            *(float4*)&bF[4] = *(const float4*)&Bs[k][gn * 8 + 4];
            #pragma unroll
            for (int i = 0; i < 8; i++)
                #pragma unroll
                for (int j = 0; j < 8; j++) acc[i][j] += aF[i] * bF[j];
        }
    }

    // per-row tile-max: thread covers rows gm*8..+7, cols gn*8..+7.
    // tile half = gn>>3; reduce across the 8 lanes sharing gm and gn>>3.
    #pragma unroll
    for (int i = 0; i < 8; i++) {
        float m = acc[i][0];
        #pragma unroll
        for (int j = 1; j < 8; j++) m = fmaxf(m, acc[i][j]);
        #pragma unroll
        for (int s = 1; s < 8; s <<= 1) m = fmaxf(m, __shfl_xor(m, s));
        if ((gn & 7) == 0) {
            int lrow = blockIdx.x * 128 + gm * 8 + i;        // stripe-local row
            int tile = blockIdx.y * 2 + (gn >> 3);
            simmax[(size_t)lrow * NT + tile] = m;
        }
    }

    #pragma unroll
    for (int i = 0; i < 8; i++) {
        size_t r = (size_t)(blockIdx.x * 128 + gm * 8 + i) * SIMN + bn0 + gn * 8;
        *(float4*)&sim[r]     = make_float4(acc[i][0], acc[i][1], acc[i][2], acc[i][3]);
        *(float4*)&sim[r + 4] = make_float4(acc[i][4], acc[i][5], acc[i][6], acc[i][7]);
    }
}

// ---------------------------------------------------------------------------
// Top-k v3: tile-max pruning. 256 threads per row.
// L = 32nd-largest tile-max (a real element) lower-bounds the 32nd-largest
// element; scan only tiles with max >= L (~32 of 256). Then per-lane top-8,
// per-wave top-32 shuffle extraction, 4-way merge of sorted lists, fp64
// re-rank -> exact top-17.
// ---------------------------------------------------------------------------
__device__ __forceinline__ void ins8(float v, int j, float lval[8], int lidx[8],
                                     float& vmin, int& pmin)
{
    if (v > vmin) {
        #pragma unroll
        for (int i = 0; i < 8; i++) if (i == pmin) { lval[i] = v; lidx[i] = j; }
        vmin = lval[0]; pmin = 0;
        #pragma unroll
        for (int i = 1; i < 8; i++) if (lval[i] < vmin) { vmin = lval[i]; pmin = i; }
    }
}

__global__ __launch_bounds__(256)
void k_topk(const float* __restrict__ sim, const float* __restrict__ simmax,
            int row0, const double* __restrict__ zn64, const float* __restrict__ zn32,
            int* __restrict__ nbr, int use64)
{
    const int lr   = blockIdx.x;
    const int r    = row0 + lr;
    const int tid  = threadIdx.x;
    const int lane = tid & 63;
    const int wv   = tid >> 6;

    __shared__ float Lsh;
    __shared__ int   tlist[64];
    __shared__ int   tcnt;
    const float* mrow = simmax + (size_t)lr * NT;

    if (tid == 0) tcnt = 0;

    // ---- phase 0: wave 0 finds the 32nd-largest tile-max ----
    if (wv == 0) {
        float4 t4 = ((const float4*)mrow)[lane];
        float v4[4] = { t4.x, t4.y, t4.z, t4.w };
        float lm = v4[0]; int ls = 0;
        #pragma unroll
        for (int i = 1; i < 4; i++) if (v4[i] > lm) { lm = v4[i]; ls = i; }
        float Lv = lm;
        for (int rd = 0; rd < 32; rd++) {
            float m = lm; int src = lane;
            #pragma unroll
            for (int mask = 1; mask < 64; mask <<= 1) {
                float om  = __shfl_xor(m, mask);
                int   osc = __shfl_xor(src, mask);
                if (om > m || (om == m && osc < src)) { m = om; src = osc; }
            }
            Lv = m;
            if (lane == src) {
                #pragma unroll
                for (int i = 0; i < 4; i++) if (i == ls) v4[i] = -3.0e38f;
                lm = v4[0]; ls = 0;
                #pragma unroll
                for (int i = 1; i < 4; i++) if (v4[i] > lm) { lm = v4[i]; ls = i; }
            }
        }
        if (lane == 0) Lsh = Lv;
    }
    __syncthreads();
    const float L = Lsh;

    // ---- survivors ----
    {
        float mv = mrow[tid];
        if (mv >= L) { int p = atomicAdd(&tcnt, 1); if (p < 64) tlist[p] = tid; }
    }
    __syncthreads();
    const int Scnt = tcnt < 64 ? tcnt : 64;

    // ---- phase 1: scan surviving tiles only ----
    float lval[8]; int lidx[8];
    #pragma unroll
    for (int i = 0; i < 8; i++) { lval[i] = -3.0e38f; lidx[i] = 0; }
    float vmin = -3.0e38f; int pmin = 0;

    const float* srow = sim + (size_t)lr * SIMN;
    const int total4 = Scnt * (TW / 4);
    for (int idx = tid; idx < total4; idx += 256) {
        int tile = tlist[idx >> 4];
        int col0 = tile * TW + (idx & 15) * 4;
        float4 v = *(const float4*)(srow + col0);
        ins8(v.x, col0 + 0, lval, lidx, vmin, pmin);
        ins8(v.y, col0 + 1, lval, lidx, vmin, pmin);
        ins8(v.z, col0 + 2, lval, lidx, vmin, pmin);
        ins8(v.w, col0 + 3, lval, lidx, vmin, pmin);
    }

    // ---- phase 2: per-wave top-32 extraction (sorted descending) ----
    __shared__ float wcv[128];
    __shared__ int   wci[128];

    float lm = -3.0e38f; int lmslot = 0;
    #pragma unroll
    for (int i = 0; i < 8; i++) if (lval[i] > lm) { lm = lval[i]; lmslot = i; }
    int lmidx = 0;
    #pragma unroll
    for (int i = 0; i < 8; i++) if (i == lmslot) lmidx = lidx[i];

    for (int rd = 0; rd < 32; rd++) {
        float m = lm; int src = lane; int midx = lmidx;
        #pragma unroll
        for (int mask = 1; mask < 64; mask <<= 1) {
            float om  = __shfl_xor(m, mask);
            int   osc = __shfl_xor(src, mask);
            int   omx = __shfl_xor(midx, mask);
            if (om > m || (om == m && omx < midx)) { m = om; src = osc; midx = omx; }
        }
        if (lane == 0) { wcv[wv * 32 + rd] = m; wci[wv * 32 + rd] = midx; }
        if (lane == src) {
            #pragma unroll
            for (int i = 0; i < 8; i++) if (i == lmslot) lval[i] = -3.0e38f;
            lm = -3.0e38f; lmslot = 0;
            #pragma unroll
            for (int i = 0; i < 8; i++) if (lval[i] > lm) { lm = lval[i]; lmslot = i; }
            lmidx = 0;
            #pragma unroll
            for (int i = 0; i < 8; i++) if (i == lmslot) lmidx = lidx[i];
        }
    }
    __syncthreads();

    // ---- phase 3: 4-way merge of the four sorted lists -> top-32 ----
    __shared__ int gi[32];
    if (tid == 0) {
        int h[4] = {0, 0, 0, 0};
        for (int t = 0; t < 32; t++) {
            float bv = -3.0e38f; int bw = 0;
            #pragma unroll
            for (int w = 0; w < 4; w++) {
                if (h[w] < 32) { float v = wcv[w * 32 + h[w]]; if (v > bv) { bv = v; bw = w; } }
            }
            gi[t] = wci[bw * 32 + h[bw]];
            h[bw]++;
        }
    }
    __syncthreads();

    // ---- phase 4: fp64 re-rank of 32 candidates -> exact top-17 ----
    __shared__ double q[CC];
    if (tid < CC) {
        q[tid] = use64 ? zn64[(size_t)r * CC + tid] : (double)zn32[(size_t)r * CC + tid];
    }
    __syncthreads();
    __shared__ double dv[32];
    if (tid < 32) {
        int cidx = gi[tid];
        if ((unsigned)cidx >= (unsigned)NN) cidx = 0;
        double s = 0.0;
        if (use64) {
            const double* zr = zn64 + (size_t)cidx * CC;
            for (int k = 0; k < CC; k++) s += q[k] * zr[k];
        } else {
            const float* zr = zn32 + (size_t)cidx * CC;
            for (int k = 0; k < CC; k++) s += q[k] * (double)zr[k];
        }
        dv[tid] = s;
    }
    __syncthreads();
    if (tid == 0) {
        unsigned used = 0u;
        for (int t = 0; t < KP1; t++) {
            double bv = 0.0; int bidx = 0; int bpos = 0; bool found = false;
            for (int i = 0; i < 32; i++) {
                if (used & (1u << i)) continue;
                double v = dv[i]; int ix = gi[i];
                if (!found || v > bv || (v == bv && ix < bidx)) { bv = v; bidx = ix; bpos = i; found = true; }
            }
            used |= (1u << bpos);
            nbr[(size_t)r * KP1 + t] = bidx;
        }
    }
}

// ---------------------------------------------------------------------------
// CSR build: count -> scan(256 threads) -> fill. All index-guarded.
// ---------------------------------------------------------------------------
__global__ __launch_bounds__(256)
void k_count(const int* __restrict__ nbr, int* __restrict__ deg)
{
    int e = blockIdx.x * 256 + threadIdx.x;
    if (e >= NN * KP1) return;
    int i = e / KP1;
    int dst = nbr[e];
    if (dst != i && (unsigned)dst < (unsigned)NN) atomicAdd(&deg[dst], 1);
}

__global__ __launch_bounds__(256)
void k_scan(const int* __restrict__ deg, int* __restrict__ rp, int* __restrict__ wp)
{
    __shared__ int s[256];
    __shared__ int carry;
    const int tid = threadIdx.x;
    if (tid == 0) carry = 0;
    __syncthreads();
    for (int ch = 0; ch < NN / 256; ch++) {
        int v = deg[ch * 256 + tid];
        s[tid] = v;
        __syncthreads();
        for (int off2 = 1; off2 < 256; off2 <<= 1) {
            int t = (tid >= off2) ? s[tid - off2] : 0;
            __syncthreads();
            s[tid] += t;
            __syncthreads();
        }
        int inc = s[tid];
        int base = carry;
        rp[ch * 256 + tid + 1] = base + inc;
        wp[ch * 256 + tid]     = base + inc - v;
        __syncthreads();
        if (tid == 255) carry = base + inc;
        __syncthreads();
    }
    if (tid == 0) rp[0] = 0;
}

__global__ __launch_bounds__(256)
void k_fill(const int* __restrict__ nbr, int* __restrict__ wp, int* __restrict__ es)
{
    int e = blockIdx.x * 256 + threadIdx.x;
    if (e >= NN * KP1) return;
    int i = e / KP1;
    int dst = nbr[e];
    if (dst != i && (unsigned)dst < (unsigned)NN) {
        int pos = atomicAdd(&wp[dst], 1);
        if ((unsigned)pos < (unsigned)(NN * KP1)) es[pos] = i;
    }
}

// ---------------------------------------------------------------------------
// Mean of in-neighbors
// ---------------------------------------------------------------------------
__global__ __launch_bounds__(128)
void k_gather(const float* __restrict__ x, const int* __restrict__ rp,
              const int* __restrict__ es, float* __restrict__ meanb)
{
    int n = blockIdx.x, c = threadIdx.x;
    int b = rp[n], e2 = rp[n + 1];
    if (b < 0) b = 0;
    if (e2 > NN * KP1) e2 = NN * KP1;
    float acc = 0.f;
    int cnt = 0;
    for (int t = b; t < e2; t++) {
        int s = es[t];
        if ((unsigned)s < (unsigned)NN) { acc += x[(size_t)s * CC + c]; cnt++; }
    }
    meanb[(size_t)n * CC + c] = acc / fmaxf((float)cnt, 1.0f);
}

// ---------------------------------------------------------------------------
// SAGE layer: out = relu(a@Ws + mean@Wn + b), 8 nodes/block
// ---------------------------------------------------------------------------
__global__ __launch_bounds__(128)
void k_layer(const float* __restrict__ a, const float* __restrict__ mb,
             const float* __restrict__ Ws, const float* __restrict__ Wn,
             const float* __restrict__ bias, float* __restrict__ out)
{
    __shared__ float as[8][CC], ms[8][CC];
    const int tid = threadIdx.x;
    const int n0 = blockIdx.x * 8;
    #pragma unroll
    for (int m = 0; m < 8; m++) {
        as[m][tid] = a[(size_t)(n0 + m) * CC + tid];
        ms[m][tid] = mb[(size_t)(n0 + m) * CC + tid];
    }
    __syncthreads();
    float acc[8];
    #pragma unroll
    for (int m = 0; m < 8; m++) acc[m] = bias[tid];
    for (int j = 0; j < CC; j++) {
        float ws = Ws[j * CC + tid], wn = Wn[j * CC + tid];
        #pragma unroll
        for (int m = 0; m < 8; m++) acc[m] += as[m][j] * ws + ms[m][j] * wn;
    }
    #pragma unroll
    for (int m = 0; m < 8; m++)
        out[(size_t)(n0 + m) * CC + tid] = fmaxf(acc[m], 0.f);
}

// ---------------------------------------------------------------------------
// Head: out = h2 @ W_head + b_head, stored FP32 (reference returns float32)
// ---------------------------------------------------------------------------
__global__ __launch_bounds__(128)
void k_head(const float* __restrict__ h2, const float* __restrict__ W,
            const float* __restrict__ bias, float* __restrict__ out)
{
    __shared__ float hsh[8][CC];
    const int tid = threadIdx.x;
    const int n0 = blockIdx.x * 8;
    #pragma unroll
    for (int m = 0; m < 8; m++) hsh[m][tid] = h2[(size_t)(n0 + m) * CC + tid];
    __syncthreads();
    float acc[8];
    #pragma unroll
    for (int m = 0; m < 8; m++) acc[m] = bias[tid];
    for (int j = 0; j < CC; j++) {
        float w = W[j * OO + tid];
        #pragma unroll
        for (int m = 0; m < 8; m++) acc[m] += hsh[m][j] * w;
    }
    #pragma unroll
    for (int m = 0; m < 8; m++)
        out[(size_t)(n0 + m) * OO + tid] = acc[m];
}

// ---------------------------------------------------------------------------
extern "C" void kernel_launch(void* const* d_in, const int* in_sizes, int n_in,
                              void* d_out, int out_size, void* d_ws, size_t ws_size,
                              hipStream_t stream)
{
    const float* x_raw      = (const float*)d_in[0];
    const float* eps        = (const float*)d_in[1];
    const float* col_logit  = (const float*)d_in[2];
    const float* type_logit = (const float*)d_in[3];
    const float* W_enc      = (const float*)d_in[4];
    const float* b_enc      = (const float*)d_in[5];
    const float* W_mu       = (const float*)d_in[6];
    const float* b_mu       = (const float*)d_in[7];
    const float* W_lv       = (const float*)d_in[8];
    const float* b_lv       = (const float*)d_in[9];
    const float* W_self1    = (const float*)d_in[10];
    const float* W_nbr1     = (const float*)d_in[11];
    const float* b1         = (const float*)d_in[12];
    const float* W_self2    = (const float*)d_in[13];
    const float* W_nbr2     = (const float*)d_in[14];
    const float* b2         = (const float*)d_in[15];
    const float* W_head     = (const float*)d_in[16];
    const float* b_head     = (const float*)d_in[17];
    float* out              = (float*)d_out;   // fp32 output, per reference dtype

    char* base = (char*)d_ws;
    size_t off = 0;
    auto alloc = [&](size_t bytes) { size_t o = off; off = (off + bytes + 255) & ~(size_t)255; return o; };

    const size_t MAT  = (size_t)NN * CC * 4;   // 8.39 MB

    float* z32    = (float*)(base + alloc(MAT));
    float* zn32   = (float*)(base + alloc(MAT));
    float* slotD  = (float*)(base + alloc(MAT));   // sim (S=128 overlay) then h1
    float* meanb  = (float*)(base + alloc(MAT));
    float* simmax = (float*)(base + alloc((size_t)2048 * NT * 4));  // 2 MB (max stripe)
    int*   nbr    = (int*)(base + alloc((size_t)NN * KP1 * 4));
    int*   deg    = (int*)(base + alloc((size_t)NN * 4));
    int*   rp     = (int*)(base + alloc((size_t)(NN + 1) * 4));
    int*   wp     = (int*)(base + alloc((size_t)NN * 4));
    int*   es     = (int*)(base + alloc((size_t)NN * KP1 * 4));
    size_t fixed_small = off;                     // ~38.4 MB

    // optional fp64 zn (16.78 MB)
    int use64 = (ws_size >= fixed_small + (size_t)NN * CC * 8 + 4096) ? 1 : 0;
    double* zn64 = nullptr;
    if (use64) zn64 = (double*)(base + alloc((size_t)NN * CC * 8));

    // optional dedicated sim stripe beyond the fixed pool
    size_t avail = (ws_size > off) ? (ws_size - off - 4096) : 0;
    int S = 2048;
    while (S > 128 && (size_t)S * SIMN * 4 > avail) S >>= 1;
    float* sim;
    if ((size_t)S * SIMN * 4 <= avail && S > 128) {
        sim = (float*)(base + alloc((size_t)S * SIMN * 4));
    } else {
        S = 128;                                  // overlay: fits exactly in slotD
        sim = slotD;
    }

    float* h1 = slotD;                            // after stripes, slotD becomes h1
    float* h2 = zn32;                             // zn32 dead after topk

    k_init<<<(NN * KP1 + 255) / 256, 256, 0, stream>>>(deg, nbr);

    k_pre<<<NN, 128, 0, stream>>>(x_raw, eps, col_logit, type_logit,
                                  W_enc, b_enc, W_mu, b_mu, W_lv, b_lv,
                                  zn64, z32, zn32, use64);

    for (int row0 = 0; row0 < NN; row0 += S) {
        dim3 g(S / 128, SIMN / 128);
        k_sim<<<g, 256, 0, stream>>>(zn32, row0, sim, simmax);
        k_topk<<<S, 256, 0, stream>>>(sim, simmax, row0, zn64, zn32, nbr, use64);
    }

    int eb = (NN * KP1 + 255) / 256;
    k_count<<<eb, 256, 0, stream>>>(nbr, deg);
    k_scan<<<1, 256, 0, stream>>>(deg, rp, wp);
    k_fill<<<eb, 256, 0, stream>>>(nbr, wp, es);

    k_gather<<<NN, 128, 0, stream>>>(z32, rp, es, meanb);
    k_layer<<<NN / 8, 128, 0, stream>>>(z32, meanb, W_self1, W_nbr1, b1, h1);
    k_gather<<<NN, 128, 0, stream>>>(h1, rp, es, meanb);
    k_layer<<<NN / 8, 128, 0, stream>>>(h1, meanb, W_self2, W_nbr2, b2, h2);
    k_head<<<NN / 8, 128, 0, stream>>>(h2, W_head, b_head, out);

    (void)in_sizes; (void)n_in; (void)out_size;
}

// Round 9
// 1544.820 us; speedup vs baseline: 3.1626x; 1.9896x over previous
//
#include <hip/hip_runtime.h>
#include <hip/hip_bf16.h>
#include <math.h>

constexpr int NN  = 16384;
constexpr int DD  = 64;
constexpr int CC  = 128;
constexpr int OO  = 128;
constexpr int KP1 = 17;
constexpr int SIMN = 16384;
constexpr int TW  = 64;              // pruning tile width
constexpr int NT  = SIMN / TW;       // 256 tiles per row
constexpr int CCAP = 1024;           // candidate buffer cap

// ---------------------------------------------------------------------------
// Init: deg = 0, nbr = self (graceful degradation if topk were to fail)
// ---------------------------------------------------------------------------
__global__ __launch_bounds__(256)
void k_init(int* __restrict__ deg, int* __restrict__ nbr)
{
    int t = blockIdx.x * 256 + threadIdx.x;
    if (t < NN) deg[t] = 0;
    if (t < NN * KP1) nbr[t] = t / KP1;
}

// ---------------------------------------------------------------------------
// Preprocess, one node per block, 128 threads (thread = channel).
// ---------------------------------------------------------------------------
__global__ __launch_bounds__(128)
void k_pre(const float* __restrict__ x_raw, const float* __restrict__ eps,
           const float* __restrict__ col_logit, const float* __restrict__ type_logit,
           const float* __restrict__ W_enc, const float* __restrict__ b_enc,
           const float* __restrict__ W_mu, const float* __restrict__ b_mu,
           const float* __restrict__ W_lv, const float* __restrict__ b_lv,
           double* __restrict__ zn64, float* __restrict__ z32, float* __restrict__ zn32,
           int use64)
{
    const int n = blockIdx.x;
    const int c = threadIdx.x;
    __shared__ double xg[DD];
    __shared__ double hsm[CC];
    __shared__ double zsh[CC];

    if (c < DD) {
        double l = (double)col_logit[c];
        double s = 1.0 / (1.0 + exp(-l * 0.5));          // sigmoid(l / TAU), TAU=2
        double g = fmin(fmax(s * 1.2 - 0.1, 0.0), 1.0);  // * (ZETA-GAMMA) + GAMMA
        xg[c] = (double)x_raw[(size_t)n * DD + c] * g;
    }
    __syncthreads();

    double tg;
    {
        double l = (double)type_logit[0];
        double s = 1.0 / (1.0 + exp(-l * 0.5));
        tg = fmin(fmax(s * 1.2 - 0.1, 0.0), 1.0);
    }

    double h = (double)b_enc[c];
    for (int d = 0; d < DD; d++) h += xg[d] * (double)W_enc[d * CC + c];
    h *= tg;
    hsm[c] = h;
    __syncthreads();

    double mu = (double)b_mu[c], lv = (double)b_lv[c];
    for (int j = 0; j < CC; j++) {
        double hj = hsm[j];
        mu += hj * (double)W_mu[j * CC + c];
        lv += hj * (double)W_lv[j * CC + c];
    }
    lv = fmin(fmax(lv, -10.0), 10.0);
    double z = mu + (double)eps[(size_t)n * CC + c] * exp(0.5 * lv);

    zsh[c] = z * z;
    __syncthreads();
    for (int off2 = 64; off2 > 0; off2 >>= 1) {
        if (c < off2) zsh[c] += zsh[c + off2];
        __syncthreads();
    }
    double rs = 1.0 / sqrt(zsh[0] + 1e-12);
    double zn = z * rs;

    size_t o = (size_t)n * CC + c;
    if (use64) zn64[o] = zn;
    z32[o]  = (float)z;
    zn32[o] = (float)zn;
}

// ---------------------------------------------------------------------------
// Sim stripe GEMM (fp32 VALU): C tile 128x128, 256 threads, 8x8 per thread.
// Also emits per-row per-64-col tile maxes (stripe-local rows) for pruning.
// ---------------------------------------------------------------------------
__global__ __launch_bounds__(256)
void k_sim(const float* __restrict__ zn, int row0, float* __restrict__ sim,
           float* __restrict__ simmax)
{
    __shared__ __align__(16) float As[32][132];
    __shared__ __align__(16) float Bs[32][132];
    const int tid = threadIdx.x;
    const int gm = tid >> 4;
    const int gn = tid & 15;
    float acc[8][8];
    #pragma unroll
    for (int i = 0; i < 8; i++)
        #pragma unroll
        for (int j = 0; j < 8; j++) acc[i][j] = 0.f;

    const int am0 = row0 + blockIdx.x * 128;
    const int bn0 = blockIdx.y * 128;
    const int lm  = tid & 127;
    const int lk  = (tid >> 7) * 16;

    for (int k0 = 0; k0 < CC; k0 += 32) {
        const float4* ap = (const float4*)(zn + (size_t)(am0 + lm) * CC + k0 + lk);
        const float4* bp = (const float4*)(zn + (size_t)(bn0 + lm) * CC + k0 + lk);
        float av[16], bv[16];
        *(float4*)&av[0]  = ap[0]; *(float4*)&av[4]  = ap[1];
        *(float4*)&av[8]  = ap[2]; *(float4*)&av[12] = ap[3];
        *(float4*)&bv[0]  = bp[0]; *(float4*)&bv[4]  = bp[1];
        *(float4*)&bv[8]  = bp[2]; *(float4*)&bv[12] = bp[3];
        __syncthreads();
        #pragma unroll
        for (int i = 0; i < 16; i++) { As[lk + i][lm] = av[i]; Bs[lk + i][lm] = bv[i]; }
        __syncthreads();
        #pragma unroll 8
        for (int k = 0; k < 32; k++) {
            float aF[8], bF[8];
            *(float4*)&aF[0] = *(const float4*)&As[k][gm * 8];
            *(float4*)&aF[4] = *(const float4*)&As[k][gm * 8 + 4];
            *(float4*)&bF[0] = *(const float4*)&Bs[k][gn * 8];
            *(float4*)&bF[4] = *(const float4*)&Bs[k][gn * 8 + 4];
            #pragma unroll
            for (int i = 0; i < 8; i++)
                #pragma unroll
                for (int j = 0; j < 8; j++) acc[i][j] += aF[i] * bF[j];
        }
    }

    // per-row tile-max (64-wide halves of the 128-col block)
    #pragma unroll
    for (int i = 0; i < 8; i++) {
        float m = acc[i][0];
        #pragma unroll
        for (int j = 1; j < 8; j++) m = fmaxf(m, acc[i][j]);
        #pragma unroll
        for (int s = 1; s < 8; s <<= 1) m = fmaxf(m, __shfl_xor(m, s));
        if ((gn & 7) == 0) {
            int lrow = blockIdx.x * 128 + gm * 8 + i;        // stripe-local row
            int tile = blockIdx.y * 2 + (gn >> 3);
            simmax[(size_t)lrow * NT + tile] = m;
        }
    }

    #pragma unroll
    for (int i = 0; i < 8; i++) {
        size_t r = (size_t)(blockIdx.x * 128 + gm * 8 + i) * SIMN + bn0 + gn * 8;
        *(float4*)&sim[r]     = make_float4(acc[i][0], acc[i][1], acc[i][2], acc[i][3]);
        *(float4*)&sim[r + 4] = make_float4(acc[i][4], acc[i][5], acc[i][6], acc[i][7]);
    }
}

// ---------------------------------------------------------------------------
// Top-k v4: rank-count selection everywhere (no serial loops, no butterflies).
// P0: L = 32nd-largest tile-max (all-pairs rank over 256, LDS broadcast).
// P1: scan surviving tiles; append every element >= L to candidate buffer.
// P2: top-32 = candidates with lex-rank < 32.
// P3: fp64 re-rank of 32. P4: rank-count -> top-17 written by rank.
// ---------------------------------------------------------------------------
__global__ __launch_bounds__(256)
void k_topk(const float* __restrict__ sim, const float* __restrict__ simmax,
            int row0, const double* __restrict__ zn64, const float* __restrict__ zn32,
            int* __restrict__ nbr, int use64)
{
    const int lr  = blockIdx.x;
    const int r   = row0 + lr;
    const int tid = threadIdx.x;

    __shared__ float  smax[NT];
    __shared__ float  Lsh;
    __shared__ int    tlist[NT];
    __shared__ int    tcnt;
    __shared__ float  cval[CCAP];
    __shared__ int    cidx[CCAP];
    __shared__ int    ccnt;
    __shared__ int    gi[32];
    __shared__ double q[CC];
    __shared__ double dv[32];

    if (tid == 0) { tcnt = 0; ccnt = 0; }
    if (tid < 32) gi[tid] = r;               // safe default (self), overwritten below
    smax[tid] = simmax[(size_t)lr * NT + tid];
    __syncthreads();

    // ---- P0: 32nd-largest tile-max via rank count ----
    {
        float v = smax[tid];
        int rank = 0;
        for (int j = 0; j < NT; j++) {
            float w = smax[j];
            rank += (w > v || (w == v && j < tid)) ? 1 : 0;
        }
        if (rank == 31) Lsh = v;
    }
    __syncthreads();
    const float L = Lsh;

    // ---- P1a: surviving tile list ----
    if (smax[tid] >= L) { int p = atomicAdd(&tcnt, 1); tlist[p] = tid; }
    __syncthreads();
    const int Scnt = tcnt;

    // ---- P1b: scan survivors, append candidates >= L ----
    const float* srow = sim + (size_t)lr * SIMN;
    const int total4 = Scnt * (TW / 4);
    for (int idx = tid; idx < total4; idx += 256) {
        int tile = tlist[idx >> 4];
        int col0 = tile * TW + (idx & 15) * 4;
        float4 v = *(const float4*)(srow + col0);
        float m4 = fmaxf(fmaxf(v.x, v.y), fmaxf(v.z, v.w));
        if (m4 >= L) {
            if (v.x >= L) { int p = atomicAdd(&ccnt, 1); if (p < CCAP) { cval[p] = v.x; cidx[p] = col0 + 0; } }
            if (v.y >= L) { int p = atomicAdd(&ccnt, 1); if (p < CCAP) { cval[p] = v.y; cidx[p] = col0 + 1; } }
            if (v.z >= L) { int p = atomicAdd(&ccnt, 1); if (p < CCAP) { cval[p] = v.z; cidx[p] = col0 + 2; } }
            if (v.w >= L) { int p = atomicAdd(&ccnt, 1); if (p < CCAP) { cval[p] = v.w; cidx[p] = col0 + 3; } }
        }
    }
    __syncthreads();
    int C = ccnt; if (C > CCAP) C = CCAP;

    // ---- P2: top-32 by lex rank over candidates ----
    for (int c = tid; c < C; c += 256) {
        float v = cval[c]; int ix = cidx[c];
        int rank = 0;
        for (int j = 0; j < C; j++) {
            float w = cval[j];
            rank += (w > v || (w == v && cidx[j] < ix)) ? 1 : 0;
        }
        if (rank < 32) gi[rank] = ix;
    }
    __syncthreads();

    // ---- P3: fp64 re-rank of 32 candidates ----
    if (tid < CC) {
        q[tid] = use64 ? zn64[(size_t)r * CC + tid] : (double)zn32[(size_t)r * CC + tid];
    }
    __syncthreads();
    if (tid < 32) {
        int cx = gi[tid];
        if ((unsigned)cx >= (unsigned)NN) cx = 0;
        double s = 0.0;
        if (use64) {
            const double* zr = zn64 + (size_t)cx * CC;
            for (int k = 0; k < CC; k++) s += q[k] * zr[k];
        } else {
            const float* zr = zn32 + (size_t)cx * CC;
            for (int k = 0; k < CC; k++) s += q[k] * (double)zr[k];
        }
        dv[tid] = s;
    }
    __syncthreads();

    // ---- P4: top-17 by rank count over the 32 (order in nbr irrelevant) ----
    if (tid < 32) {
        double v = dv[tid]; int ix = gi[tid];
        int rank = 0;
        for (int j = 0; j < 32; j++) {
            double w = dv[j];
            rank += (w > v || (w == v && gi[j] < ix)) ? 1 : 0;
        }
        if (rank < KP1) nbr[(size_t)r * KP1 + rank] = ix;
    }
}

// ---------------------------------------------------------------------------
// CSR build: count -> scan(256 threads) -> fill. All index-guarded.
// ---------------------------------------------------------------------------
__global__ __launch_bounds__(256)
void k_count(const int* __restrict__ nbr, int* __restrict__ deg)
{
    int e = blockIdx.x * 256 + threadIdx.x;
    if (e >= NN * KP1) return;
    int i = e / KP1;
    int dst = nbr[e];
    if (dst != i && (unsigned)dst < (unsigned)NN) atomicAdd(&deg[dst], 1);
}

__global__ __launch_bounds__(256)
void k_scan(const int* __restrict__ deg, int* __restrict__ rp, int* __restrict__ wp)
{
    __shared__ int s[256];
    __shared__ int carry;
    const int tid = threadIdx.x;
    if (tid == 0) carry = 0;
    __syncthreads();
    for (int ch = 0; ch < NN / 256; ch++) {
        int v = deg[ch * 256 + tid];
        s[tid] = v;
        __syncthreads();
        for (int off2 = 1; off2 < 256; off2 <<= 1) {
            int t = (tid >= off2) ? s[tid - off2] : 0;
            __syncthreads();
            s[tid] += t;
            __syncthreads();
        }
        int inc = s[tid];
        int base = carry;
        rp[ch * 256 + tid + 1] = base + inc;
        wp[ch * 256 + tid]     = base + inc - v;
        __syncthreads();
        if (tid == 255) carry = base + inc;
        __syncthreads();
    }
    if (tid == 0) rp[0] = 0;
}

__global__ __launch_bounds__(256)
void k_fill(const int* __restrict__ nbr, int* __restrict__ wp, int* __restrict__ es)
{
    int e = blockIdx.x * 256 + threadIdx.x;
    if (e >= NN * KP1) return;
    int i = e / KP1;
    int dst = nbr[e];
    if (dst != i && (unsigned)dst < (unsigned)NN) {
        int pos = atomicAdd(&wp[dst], 1);
        if ((unsigned)pos < (unsigned)(NN * KP1)) es[pos] = i;
    }
}

// ---------------------------------------------------------------------------
// Mean of in-neighbors
// ---------------------------------------------------------------------------
__global__ __launch_bounds__(128)
void k_gather(const float* __restrict__ x, const int* __restrict__ rp,
              const int* __restrict__ es, float* __restrict__ meanb)
{
    int n = blockIdx.x, c = threadIdx.x;
    int b = rp[n], e2 = rp[n + 1];
    if (b < 0) b = 0;
    if (e2 > NN * KP1) e2 = NN * KP1;
    float acc = 0.f;
    int cnt = 0;
    for (int t = b; t < e2; t++) {
        int s = es[t];
        if ((unsigned)s < (unsigned)NN) { acc += x[(size_t)s * CC + c]; cnt++; }
    }
    meanb[(size_t)n * CC + c] = acc / fmaxf((float)cnt, 1.0f);
}

// ---------------------------------------------------------------------------
// SAGE layer: out = relu(a@Ws + mean@Wn + b), 8 nodes/block
// ---------------------------------------------------------------------------
__global__ __launch_bounds__(128)
void k_layer(const float* __restrict__ a, const float* __restrict__ mb,
             const float* __restrict__ Ws, const float* __restrict__ Wn,
             const float* __restrict__ bias, float* __restrict__ out)
{
    __shared__ float as[8][CC], ms[8][CC];
    const int tid = threadIdx.x;
    const int n0 = blockIdx.x * 8;
    #pragma unroll
    for (int m = 0; m < 8; m++) {
        as[m][tid] = a[(size_t)(n0 + m) * CC + tid];
        ms[m][tid] = mb[(size_t)(n0 + m) * CC + tid];
    }
    __syncthreads();
    float acc[8];
    #pragma unroll
    for (int m = 0; m < 8; m++) acc[m] = bias[tid];
    for (int j = 0; j < CC; j++) {
        float ws = Ws[j * CC + tid], wn = Wn[j * CC + tid];
        #pragma unroll
        for (int m = 0; m < 8; m++) acc[m] += as[m][j] * ws + ms[m][j] * wn;
    }
    #pragma unroll
    for (int m = 0; m < 8; m++)
        out[(size_t)(n0 + m) * CC + tid] = fmaxf(acc[m], 0.f);
}

// ---------------------------------------------------------------------------
// Head: out = h2 @ W_head + b_head, stored FP32 (reference returns float32)
// ---------------------------------------------------------------------------
__global__ __launch_bounds__(128)
void k_head(const float* __restrict__ h2, const float* __restrict__ W,
            const float* __restrict__ bias, float* __restrict__ out)
{
    __shared__ float hsh[8][CC];
    const int tid = threadIdx.x;
    const int n0 = blockIdx.x * 8;
    #pragma unroll
    for (int m = 0; m < 8; m++) hsh[m][tid] = h2[(size_t)(n0 + m) * CC + tid];
    __syncthreads();
    float acc[8];
    #pragma unroll
    for (int m = 0; m < 8; m++) acc[m] = bias[tid];
    for (int j = 0; j < CC; j++) {
        float w = W[j * OO + tid];
        #pragma unroll
        for (int m = 0; m < 8; m++) acc[m] += hsh[m][j] * w;
    }
    #pragma unroll
    for (int m = 0; m < 8; m++)
        out[(size_t)(n0 + m) * OO + tid] = acc[m];
}

// ---------------------------------------------------------------------------
extern "C" void kernel_launch(void* const* d_in, const int* in_sizes, int n_in,
                              void* d_out, int out_size, void* d_ws, size_t ws_size,
                              hipStream_t stream)
{
    const float* x_raw      = (const float*)d_in[0];
    const float* eps        = (const float*)d_in[1];
    const float* col_logit  = (const float*)d_in[2];
    const float* type_logit = (const float*)d_in[3];
    const float* W_enc      = (const float*)d_in[4];
    const float* b_enc      = (const float*)d_in[5];
    const float* W_mu       = (const float*)d_in[6];
    const float* b_mu       = (const float*)d_in[7];
    const float* W_lv       = (const float*)d_in[8];
    const float* b_lv       = (const float*)d_in[9];
    const float* W_self1    = (const float*)d_in[10];
    const float* W_nbr1     = (const float*)d_in[11];
    const float* b1         = (const float*)d_in[12];
    const float* W_self2    = (const float*)d_in[13];
    const float* W_nbr2     = (const float*)d_in[14];
    const float* b2         = (const float*)d_in[15];
    const float* W_head     = (const float*)d_in[16];
    const float* b_head     = (const float*)d_in[17];
    float* out              = (float*)d_out;   // fp32 output, per reference dtype

    char* base = (char*)d_ws;
    size_t off = 0;
    auto alloc = [&](size_t bytes) { size_t o = off; off = (off + bytes + 255) & ~(size_t)255; return o; };

    const size_t MAT  = (size_t)NN * CC * 4;   // 8.39 MB

    float* z32    = (float*)(base + alloc(MAT));
    float* zn32   = (float*)(base + alloc(MAT));
    float* slotD  = (float*)(base + alloc(MAT));   // sim (S=128 overlay) then h1
    float* meanb  = (float*)(base + alloc(MAT));
    float* simmax = (float*)(base + alloc((size_t)2048 * NT * 4));  // 2 MB (max stripe)
    int*   nbr    = (int*)(base + alloc((size_t)NN * KP1 * 4));
    int*   deg    = (int*)(base + alloc((size_t)NN * 4));
    int*   rp     = (int*)(base + alloc((size_t)(NN + 1) * 4));
    int*   wp     = (int*)(base + alloc((size_t)NN * 4));
    int*   es     = (int*)(base + alloc((size_t)NN * KP1 * 4));
    size_t fixed_small = off;                     // ~38.4 MB

    // optional fp64 zn (16.78 MB)
    int use64 = (ws_size >= fixed_small + (size_t)NN * CC * 8 + 4096) ? 1 : 0;
    double* zn64 = nullptr;
    if (use64) zn64 = (double*)(base + alloc((size_t)NN * CC * 8));

    // optional dedicated sim stripe beyond the fixed pool
    size_t avail = (ws_size > off) ? (ws_size - off - 4096) : 0;
    int S = 2048;
    while (S > 128 && (size_t)S * SIMN * 4 > avail) S >>= 1;
    float* sim;
    if ((size_t)S * SIMN * 4 <= avail && S > 128) {
        sim = (float*)(base + alloc((size_t)S * SIMN * 4));
    } else {
        S = 128;                                  // overlay: fits exactly in slotD
        sim = slotD;
    }

    float* h1 = slotD;                            // after stripes, slotD becomes h1
    float* h2 = zn32;                             // zn32 dead after topk

    k_init<<<(NN * KP1 + 255) / 256, 256, 0, stream>>>(deg, nbr);

    k_pre<<<NN, 128, 0, stream>>>(x_raw, eps, col_logit, type_logit,
                                  W_enc, b_enc, W_mu, b_mu, W_lv, b_lv,
                                  zn64, z32, zn32, use64);

    for (int row0 = 0; row0 < NN; row0 += S) {
        dim3 g(S / 128, SIMN / 128);
        k_sim<<<g, 256, 0, stream>>>(zn32, row0, sim, simmax);
        k_topk<<<S, 256, 0, stream>>>(sim, simmax, row0, zn64, zn32, nbr, use64);
    }

    int eb = (NN * KP1 + 255) / 256;
    k_count<<<eb, 256, 0, stream>>>(nbr, deg);
    k_scan<<<1, 256, 0, stream>>>(deg, rp, wp);
    k_fill<<<eb, 256, 0, stream>>>(nbr, wp, es);

    k_gather<<<NN, 128, 0, stream>>>(z32, rp, es, meanb);
    k_layer<<<NN / 8, 128, 0, stream>>>(z32, meanb, W_self1, W_nbr1, b1, h1);
    k_gather<<<NN, 128, 0, stream>>>(h1, rp, es, meanb);
    k_layer<<<NN / 8, 128, 0, stream>>>(h1, meanb, W_self2, W_nbr2, b2, h2);
    k_head<<<NN / 8, 128, 0, stream>>>(h2, W_head, b_head, out);

    (void)in_sizes; (void)n_in; (void)out_size;
}

// Round 10
// 981.643 us; speedup vs baseline: 4.9769x; 1.5737x over previous
//
#include <hip/hip_runtime.h>
#include <hip/hip_bf16.h>
#include <math.h>

constexpr int NN  = 16384;
constexpr int DD  = 64;
constexpr int CC  = 128;
constexpr int OO  = 128;
constexpr int KP1 = 17;
constexpr int SIMN = 16384;
constexpr int TW  = 64;              // pruning tile width
constexpr int NT  = SIMN / TW;       // 256 tiles per row
constexpr int CCAP = 1024;           // candidate buffer cap

typedef __attribute__((ext_vector_type(8))) short short8;
typedef __attribute__((ext_vector_type(4))) float floatx4;

__device__ __forceinline__ float bf2f(unsigned short u) {
    union { unsigned u; float f; } c; c.u = ((unsigned)u) << 16; return c.f;
}
__device__ __forceinline__ unsigned short f2bf(float f) {
    union { float f; unsigned u; } c; c.f = f;
    unsigned b = c.u;
    return (unsigned short)((b + 0x7FFFu + ((b >> 16) & 1u)) >> 16);
}

// ---------------------------------------------------------------------------
// Init: deg = 0, nbr = self
// ---------------------------------------------------------------------------
__global__ __launch_bounds__(256)
void k_init(int* __restrict__ deg, int* __restrict__ nbr)
{
    int t = blockIdx.x * 256 + threadIdx.x;
    if (t < NN) deg[t] = 0;
    if (t < NN * KP1) nbr[t] = t / KP1;
}

// ---------------------------------------------------------------------------
// Preprocess, one node per block, 128 threads. fp64 math from fp32 inputs.
// Emits zn64 (optional), z32, zn32, znb (bf16 zn for MFMA sim).
// ---------------------------------------------------------------------------
__global__ __launch_bounds__(128)
void k_pre(const float* __restrict__ x_raw, const float* __restrict__ eps,
           const float* __restrict__ col_logit, const float* __restrict__ type_logit,
           const float* __restrict__ W_enc, const float* __restrict__ b_enc,
           const float* __restrict__ W_mu, const float* __restrict__ b_mu,
           const float* __restrict__ W_lv, const float* __restrict__ b_lv,
           double* __restrict__ zn64, float* __restrict__ z32, float* __restrict__ zn32,
           unsigned short* __restrict__ znb, int use64)
{
    const int n = blockIdx.x;
    const int c = threadIdx.x;
    __shared__ double xg[DD];
    __shared__ double hsm[CC];
    __shared__ double zsh[CC];

    if (c < DD) {
        double l = (double)col_logit[c];
        double s = 1.0 / (1.0 + exp(-l * 0.5));          // sigmoid(l / TAU), TAU=2
        double g = fmin(fmax(s * 1.2 - 0.1, 0.0), 1.0);  // * (ZETA-GAMMA) + GAMMA
        xg[c] = (double)x_raw[(size_t)n * DD + c] * g;
    }
    __syncthreads();

    double tg;
    {
        double l = (double)type_logit[0];
        double s = 1.0 / (1.0 + exp(-l * 0.5));
        tg = fmin(fmax(s * 1.2 - 0.1, 0.0), 1.0);
    }

    double h = (double)b_enc[c];
    for (int d = 0; d < DD; d++) h += xg[d] * (double)W_enc[d * CC + c];
    h *= tg;
    hsm[c] = h;
    __syncthreads();

    double mu = (double)b_mu[c], lv = (double)b_lv[c];
    for (int j = 0; j < CC; j++) {
        double hj = hsm[j];
        mu += hj * (double)W_mu[j * CC + c];
        lv += hj * (double)W_lv[j * CC + c];
    }
    lv = fmin(fmax(lv, -10.0), 10.0);
    double z = mu + (double)eps[(size_t)n * CC + c] * exp(0.5 * lv);

    zsh[c] = z * z;
    __syncthreads();
    for (int off2 = 64; off2 > 0; off2 >>= 1) {
        if (c < off2) zsh[c] += zsh[c + off2];
        __syncthreads();
    }
    double rs = 1.0 / sqrt(zsh[0] + 1e-12);
    double zn = z * rs;

    size_t o = (size_t)n * CC + c;
    if (use64) zn64[o] = zn;
    z32[o]  = (float)z;
    float znf = (float)zn;
    zn32[o] = znf;
    znb[o]  = f2bf(znf);
}

// ---------------------------------------------------------------------------
// Sim stripe GEMM via bf16 MFMA. C tile 128x128, K=128, 256 threads (4 waves,
// each a 64x64 quadrant). XOR-swizzled LDS (64 KB), conflict-free b128 frags.
// Epilogue: round C to bf16, stage via LDS, coalesced stores + 64-wide tile max.
// ---------------------------------------------------------------------------
__global__ __launch_bounds__(256)
void k_sim(const unsigned short* __restrict__ znb, int row0,
           unsigned short* __restrict__ sim, float* __restrict__ simmax)
{
    __shared__ __align__(16) unsigned short lds[2 * 128 * 128];   // 64 KB
    const int tid  = threadIdx.x;
    const int lane = tid & 63;
    const int wv   = tid >> 6;
    const int am0  = row0 + blockIdx.x * 128;
    const int bn0  = blockIdx.y * 128;

    // stage A (rows am0..+127) and B (rows bn0..+127), swizzled chunks of 8
    #pragma unroll
    for (int i = 0; i < 8; i++) {
        int linear = i * 256 + tid;          // 0..2047
        int rr = linear >> 4;                // row 0..127
        int c  = linear & 15;                // chunk 0..15
        int pc = (c ^ (rr & 15)) * 8;
        *(short8*)&lds[rr * 128 + pc] =
            *(const short8*)&znb[(size_t)(am0 + rr) * CC + c * 8];
        *(short8*)&lds[16384 + rr * 128 + pc] =
            *(const short8*)&znb[(size_t)(bn0 + rr) * CC + c * 8];
    }
    __syncthreads();

    const int mq = (wv & 1) * 64;
    const int nq = (wv >> 1) * 64;
    const int lm = lane & 15;
    const int lk = lane >> 4;                // quad 0..3

    floatx4 acc[4][4];
    #pragma unroll
    for (int i = 0; i < 4; i++)
        #pragma unroll
        for (int j = 0; j < 4; j++) acc[i][j] = (floatx4){0.f, 0.f, 0.f, 0.f};

    #pragma unroll
    for (int kt = 0; kt < 4; kt++) {
        short8 af[4], bfr[4];
        #pragma unroll
        for (int t = 0; t < 4; t++) {
            int ra = mq + t * 16 + lm;
            int rb = nq + t * 16 + lm;
            int ca = ((kt * 4 + lk) ^ (ra & 15)) * 8;
            int cb = ((kt * 4 + lk) ^ (rb & 15)) * 8;
            af[t]  = *(const short8*)&lds[ra * 128 + ca];
            bfr[t] = *(const short8*)&lds[16384 + rb * 128 + cb];
        }
        #pragma unroll
        for (int mt = 0; mt < 4; mt++)
            #pragma unroll
            for (int nt = 0; nt < 4; nt++)
                acc[mt][nt] = __builtin_amdgcn_mfma_f32_16x16x32_bf16(
                    af[mt], bfr[nt], acc[mt][nt], 0, 0, 0);
    }
    __syncthreads();   // done reading A/B; reuse region A for C staging

    // stage C (bf16) into lds[0..16384) with the same swizzle
    #pragma unroll
    for (int mt = 0; mt < 4; mt++)
        #pragma unroll
        for (int nt = 0; nt < 4; nt++)
            #pragma unroll
            for (int rg = 0; rg < 4; rg++) {
                int m = mq + mt * 16 + lk * 4 + rg;
                int n = nq + nt * 16 + lm;
                int pc = ((n >> 3) ^ (m & 15)) * 8 + (n & 7);
                lds[m * 128 + pc] = f2bf(acc[mt][nt][rg]);
            }
    __syncthreads();

    // writeout + tile max: thread -> (row = tid>>1, half = tid&1)
    {
        int rr = tid >> 1, half = tid & 1;
        int lrow = blockIdx.x * 128 + rr;
        unsigned short* dst = sim + (size_t)lrow * SIMN + bn0 + half * 64;
        float mx = -3.0e38f;
        #pragma unroll
        for (int t = 0; t < 8; t++) {
            int c = half * 8 + t;
            int pc = (c ^ (rr & 15)) * 8;
            short8 v = *(const short8*)&lds[rr * 128 + pc];
            *(short8*)&dst[t * 8] = v;
            #pragma unroll
            for (int e = 0; e < 8; e++) mx = fmaxf(mx, bf2f((unsigned short)v[e]));
        }
        simmax[(size_t)lrow * NT + blockIdx.y * 2 + half] = mx;
    }
}

// ---------------------------------------------------------------------------
// Top-k v4 (rank-count), bf16 sim input.
// ---------------------------------------------------------------------------
__global__ __launch_bounds__(256)
void k_topk(const unsigned short* __restrict__ sim, const float* __restrict__ simmax,
            int row0, const double* __restrict__ zn64, const float* __restrict__ zn32,
            int* __restrict__ nbr, int use64)
{
    const int lr  = blockIdx.x;
    const int r   = row0 + lr;
    const int tid = threadIdx.x;

    __shared__ float  smax[NT];
    __shared__ float  Lsh;
    __shared__ int    tlist[NT];
    __shared__ int    tcnt;
    __shared__ float  cval[CCAP];
    __shared__ int    cidx[CCAP];
    __shared__ int    ccnt;
    __shared__ int    gi[32];
    __shared__ double q[CC];
    __shared__ double dv[32];

    if (tid == 0) { tcnt = 0; ccnt = 0; }
    if (tid < 32) gi[tid] = r;               // safe default (self)
    smax[tid] = simmax[(size_t)lr * NT + tid];
    __syncthreads();

    // ---- P0: 32nd-largest tile-max via rank count ----
    {
        float v = smax[tid];
        int rank = 0;
        for (int j = 0; j < NT; j++) {
            float w = smax[j];
            rank += (w > v || (w == v && j < tid)) ? 1 : 0;
        }
        if (rank == 31) Lsh = v;
    }
    __syncthreads();
    const float L = Lsh;

    // ---- P1a: surviving tile list ----
    if (smax[tid] >= L) { int p = atomicAdd(&tcnt, 1); tlist[p] = tid; }
    __syncthreads();
    const int Scnt = tcnt;

    // ---- P1b: scan survivors (bf16), append candidates >= L ----
    const unsigned short* srow = sim + (size_t)lr * SIMN;
    const int total8 = Scnt * (TW / 8);
    for (int idx = tid; idx < total8; idx += 256) {
        int tile = tlist[idx >> 3];
        int col0 = tile * TW + (idx & 7) * 8;
        short8 v8 = *(const short8*)&srow[col0];
        #pragma unroll
        for (int e = 0; e < 8; e++) {
            float v = bf2f((unsigned short)v8[e]);
            if (v >= L) {
                int p = atomicAdd(&ccnt, 1);
                if (p < CCAP) { cval[p] = v; cidx[p] = col0 + e; }
            }
        }
    }
    __syncthreads();
    int C = ccnt; if (C > CCAP) C = CCAP;

    // ---- P2: top-32 by lex rank over candidates ----
    for (int c = tid; c < C; c += 256) {
        float v = cval[c]; int ix = cidx[c];
        int rank = 0;
        for (int j = 0; j < C; j++) {
            float w = cval[j];
            rank += (w > v || (w == v && cidx[j] < ix)) ? 1 : 0;
        }
        if (rank < 32) gi[rank] = ix;
    }
    __syncthreads();

    // ---- P3: fp64 re-rank of 32 candidates ----
    if (tid < CC) {
        q[tid] = use64 ? zn64[(size_t)r * CC + tid] : (double)zn32[(size_t)r * CC + tid];
    }
    __syncthreads();
    if (tid < 32) {
        int cx = gi[tid];
        if ((unsigned)cx >= (unsigned)NN) cx = 0;
        double s = 0.0;
        if (use64) {
            const double* zr = zn64 + (size_t)cx * CC;
            for (int k = 0; k < CC; k++) s += q[k] * zr[k];
        } else {
            const float* zr = zn32 + (size_t)cx * CC;
            for (int k = 0; k < CC; k++) s += q[k] * (double)zr[k];
        }
        dv[tid] = s;
    }
    __syncthreads();

    // ---- P4: top-17 by rank count over the 32 ----
    if (tid < 32) {
        double v = dv[tid]; int ix = gi[tid];
        int rank = 0;
        for (int j = 0; j < 32; j++) {
            double w = dv[j];
            rank += (w > v || (w == v && gi[j] < ix)) ? 1 : 0;
        }
        if (rank < KP1) nbr[(size_t)r * KP1 + rank] = ix;
    }
}

// ---------------------------------------------------------------------------
// CSR build: count -> scan -> fill. All index-guarded.
// ---------------------------------------------------------------------------
__global__ __launch_bounds__(256)
void k_count(const int* __restrict__ nbr, int* __restrict__ deg)
{
    int e = blockIdx.x * 256 + threadIdx.x;
    if (e >= NN * KP1) return;
    int i = e / KP1;
    int dst = nbr[e];
    if (dst != i && (unsigned)dst < (unsigned)NN) atomicAdd(&deg[dst], 1);
}

__global__ __launch_bounds__(256)
void k_scan(const int* __restrict__ deg, int* __restrict__ rp, int* __restrict__ wp)
{
    __shared__ int s[256];
    __shared__ int carry;
    const int tid = threadIdx.x;
    if (tid == 0) carry = 0;
    __syncthreads();
    for (int ch = 0; ch < NN / 256; ch++) {
        int v = deg[ch * 256 + tid];
        s[tid] = v;
        __syncthreads();
        for (int off2 = 1; off2 < 256; off2 <<= 1) {
            int t = (tid >= off2) ? s[tid - off2] : 0;
            __syncthreads();
            s[tid] += t;
            __syncthreads();
        }
        int inc = s[tid];
        int base = carry;
        rp[ch * 256 + tid + 1] = base + inc;
        wp[ch * 256 + tid]     = base + inc - v;
        __syncthreads();
        if (tid == 255) carry = base + inc;
        __syncthreads();
    }
    if (tid == 0) rp[0] = 0;
}

__global__ __launch_bounds__(256)
void k_fill(const int* __restrict__ nbr, int* __restrict__ wp, int* __restrict__ es)
{
    int e = blockIdx.x * 256 + threadIdx.x;
    if (e >= NN * KP1) return;
    int i = e / KP1;
    int dst = nbr[e];
    if (dst != i && (unsigned)dst < (unsigned)NN) {
        int pos = atomicAdd(&wp[dst], 1);
        if ((unsigned)pos < (unsigned)(NN * KP1)) es[pos] = i;
    }
}

// ---------------------------------------------------------------------------
// Mean of in-neighbors
// ---------------------------------------------------------------------------
__global__ __launch_bounds__(128)
void k_gather(const float* __restrict__ x, const int* __restrict__ rp,
              const int* __restrict__ es, float* __restrict__ meanb)
{
    int n = blockIdx.x, c = threadIdx.x;
    int b = rp[n], e2 = rp[n + 1];
    if (b < 0) b = 0;
    if (e2 > NN * KP1) e2 = NN * KP1;
    float acc = 0.f;
    int cnt = 0;
    for (int t = b; t < e2; t++) {
        int s = es[t];
        if ((unsigned)s < (unsigned)NN) { acc += x[(size_t)s * CC + c]; cnt++; }
    }
    meanb[(size_t)n * CC + c] = acc / fmaxf((float)cnt, 1.0f);
}

// ---------------------------------------------------------------------------
// SAGE layer: out = relu(a@Ws + mean@Wn + b), 8 nodes/block
// ---------------------------------------------------------------------------
__global__ __launch_bounds__(128)
void k_layer(const float* __restrict__ a, const float* __restrict__ mb,
             const float* __restrict__ Ws, const float* __restrict__ Wn,
             const float* __restrict__ bias, float* __restrict__ out)
{
    __shared__ float as[8][CC], ms[8][CC];
    const int tid = threadIdx.x;
    const int n0 = blockIdx.x * 8;
    #pragma unroll
    for (int m = 0; m < 8; m++) {
        as[m][tid] = a[(size_t)(n0 + m) * CC + tid];
        ms[m][tid] = mb[(size_t)(n0 + m) * CC + tid];
    }
    __syncthreads();
    float acc[8];
    #pragma unroll
    for (int m = 0; m < 8; m++) acc[m] = bias[tid];
    for (int j = 0; j < CC; j++) {
        float ws = Ws[j * CC + tid], wn = Wn[j * CC + tid];
        #pragma unroll
        for (int m = 0; m < 8; m++) acc[m] += as[m][j] * ws + ms[m][j] * wn;
    }
    #pragma unroll
    for (int m = 0; m < 8; m++)
        out[(size_t)(n0 + m) * CC + tid] = fmaxf(acc[m], 0.f);
}

// ---------------------------------------------------------------------------
// Head: out = h2 @ W_head + b_head, fp32 output
// ---------------------------------------------------------------------------
__global__ __launch_bounds__(128)
void k_head(const float* __restrict__ h2, const float* __restrict__ W,
            const float* __restrict__ bias, float* __restrict__ out)
{
    __shared__ float hsh[8][CC];
    const int tid = threadIdx.x;
    const int n0 = blockIdx.x * 8;
    #pragma unroll
    for (int m = 0; m < 8; m++) hsh[m][tid] = h2[(size_t)(n0 + m) * CC + tid];
    __syncthreads();
    float acc[8];
    #pragma unroll
    for (int m = 0; m < 8; m++) acc[m] = bias[tid];
    for (int j = 0; j < CC; j++) {
        float w = W[j * OO + tid];
        #pragma unroll
        for (int m = 0; m < 8; m++) acc[m] += hsh[m][j] * w;
    }
    #pragma unroll
    for (int m = 0; m < 8; m++)
        out[(size_t)(n0 + m) * OO + tid] = acc[m];
}

// ---------------------------------------------------------------------------
extern "C" void kernel_launch(void* const* d_in, const int* in_sizes, int n_in,
                              void* d_out, int out_size, void* d_ws, size_t ws_size,
                              hipStream_t stream)
{
    const float* x_raw      = (const float*)d_in[0];
    const float* eps        = (const float*)d_in[1];
    const float* col_logit  = (const float*)d_in[2];
    const float* type_logit = (const float*)d_in[3];
    const float* W_enc      = (const float*)d_in[4];
    const float* b_enc      = (const float*)d_in[5];
    const float* W_mu       = (const float*)d_in[6];
    const float* b_mu       = (const float*)d_in[7];
    const float* W_lv       = (const float*)d_in[8];
    const float* b_lv       = (const float*)d_in[9];
    const float* W_self1    = (const float*)d_in[10];
    const float* W_nbr1     = (const float*)d_in[11];
    const float* b1         = (const float*)d_in[12];
    const float* W_self2    = (const float*)d_in[13];
    const float* W_nbr2     = (const float*)d_in[14];
    const float* b2         = (const float*)d_in[15];
    const float* W_head     = (const float*)d_in[16];
    const float* b_head     = (const float*)d_in[17];
    float* out              = (float*)d_out;   // fp32 output, per reference dtype

    char* base = (char*)d_ws;
    size_t off = 0;
    auto alloc = [&](size_t bytes) { size_t o = off; off = (off + bytes + 255) & ~(size_t)255; return o; };

    const size_t MAT  = (size_t)NN * CC * 4;   // 8.39 MB

    float* z32    = (float*)(base + alloc(MAT));
    float* zn32   = (float*)(base + alloc(MAT));
    float* slotD  = (float*)(base + alloc(MAT));   // sim overlay (S=128) then h1
    float* meanb  = (float*)(base + alloc(MAT));
    unsigned short* znb = (unsigned short*)(base + alloc((size_t)NN * CC * 2));  // 4 MB
    float* simmax = (float*)(base + alloc((size_t)2048 * NT * 4));  // 2 MB (max stripe)
    int*   nbr    = (int*)(base + alloc((size_t)NN * KP1 * 4));
    int*   deg    = (int*)(base + alloc((size_t)NN * 4));
    int*   rp     = (int*)(base + alloc((size_t)(NN + 1) * 4));
    int*   wp     = (int*)(base + alloc((size_t)NN * 4));
    int*   es     = (int*)(base + alloc((size_t)NN * KP1 * 4));
    size_t fixed_small = off;

    // optional fp64 zn (16.78 MB)
    int use64 = (ws_size >= fixed_small + (size_t)NN * CC * 8 + 4096) ? 1 : 0;
    double* zn64 = nullptr;
    if (use64) zn64 = (double*)(base + alloc((size_t)NN * CC * 8));

    // sim stripe (bf16): dedicated if it fits, else S=128 overlay in slotD
    size_t avail = (ws_size > off) ? (ws_size - off - 4096) : 0;
    int S = 2048;
    while (S > 128 && (size_t)S * SIMN * 2 > avail) S >>= 1;
    unsigned short* sim;
    if ((size_t)S * SIMN * 2 <= avail && S > 128) {
        sim = (unsigned short*)(base + alloc((size_t)S * SIMN * 2));
    } else {
        S = 128;                                  // 4 MB, fits in slotD (8.39 MB)
        sim = (unsigned short*)slotD;
    }

    float* h1 = slotD;                            // after stripes, slotD becomes h1
    float* h2 = zn32;                             // zn32 dead after topk

    k_init<<<(NN * KP1 + 255) / 256, 256, 0, stream>>>(deg, nbr);

    k_pre<<<NN, 128, 0, stream>>>(x_raw, eps, col_logit, type_logit,
                                  W_enc, b_enc, W_mu, b_mu, W_lv, b_lv,
                                  zn64, z32, zn32, znb, use64);

    for (int row0 = 0; row0 < NN; row0 += S) {
        dim3 g(S / 128, SIMN / 128);
        k_sim<<<g, 256, 0, stream>>>(znb, row0, sim, simmax);
        k_topk<<<S, 256, 0, stream>>>(sim, simmax, row0, zn64, zn32, nbr, use64);
    }

    int eb = (NN * KP1 + 255) / 256;
    k_count<<<eb, 256, 0, stream>>>(nbr, deg);
    k_scan<<<1, 256, 0, stream>>>(deg, rp, wp);
    k_fill<<<eb, 256, 0, stream>>>(nbr, wp, es);

    k_gather<<<NN, 128, 0, stream>>>(z32, rp, es, meanb);
    k_layer<<<NN / 8, 128, 0, stream>>>(z32, meanb, W_self1, W_nbr1, b1, h1);
    k_gather<<<NN, 128, 0, stream>>>(h1, rp, es, meanb);
    k_layer<<<NN / 8, 128, 0, stream>>>(h1, meanb, W_self2, W_nbr2, b2, h2);
    k_head<<<NN / 8, 128, 0, stream>>>(h2, W_head, b_head, out);

    (void)in_sizes; (void)n_in; (void)out_size;
}